// Round 10
// baseline (85.598 us; speedup 1.0000x reference)
//
#include <hip/hip_runtime.h>
#include <hip/hip_bf16.h>
#include <hip/hip_fp16.h>

#define NN 4096
#define SDIM 64
#define HID 128
#define HEADS 4
#define FF 32

typedef __attribute__((ext_vector_type(8))) _Float16 h8;      // MFMA f16 A/B frag
typedef __attribute__((ext_vector_type(2))) _Float16 h2;
typedef __attribute__((ext_vector_type(4))) float f32x4;      // MFMA C/D
typedef __attribute__((ext_vector_type(4))) unsigned short us4;

__device__ inline h2 h2max(h2 a, h2 b) {
    h2 r; r[0] = a[0] > b[0] ? a[0] : b[0]; r[1] = a[1] > b[1] ? a[1] : b[1]; return r;
}

// ---------------- workspace layout (float units) ----------------
// hTf  : 0        (262144 f = 524288 fp16)  fragment-ordered h^T
// s1   : 262144   s2: 278528   (16384 each)
// E2h  : 294912   (8192 f = 16384 fp16)
// E2sh : 303104   (8192)
// cpos : 311296   cneg: 327680  (16384 each, f32)
// abit : 344064   (524288 f = 2 MB bits)
// feat : 868352   (524288 f)
// total 1392640 floats = 5.6 MB

// ============ K1: grid-partitioned prep (blocks 0..1023, 4 rows each)
//                  + adjacency bit-pack (blocks 1024..5119, 1 row each) ============
__global__ __launch_bounds__(256) void k_prep_pack(
        const float* __restrict__ state,
        const float* __restrict__ W1, const float* __restrict__ b1,
        const float* __restrict__ W2, const float* __restrict__ b2,
        const float* __restrict__ Wg, const float* __restrict__ ag,
        const int* __restrict__ adj,
        unsigned short* __restrict__ hTf,
        float* __restrict__ s1b, float* __restrict__ s2b,
        unsigned int* __restrict__ abit) {
    int tid = threadIdx.x;

    if (blockIdx.x >= 1024) {
        // ---- pack branch: thread t packs 16 ints -> ushort ----
        int r = blockIdx.x - 1024;
        const int4* ap = (const int4*)(adj + (size_t)r * NN + tid * 16);
        unsigned int b = 0;
#pragma unroll
        for (int i = 0; i < 4; i++) {
            int4 a = ap[i];
            b |= (unsigned int)(a.x != 0) << (i * 4 + 0);
            b |= (unsigned int)(a.y != 0) << (i * 4 + 1);
            b |= (unsigned int)(a.z != 0) << (i * 4 + 2);
            b |= (unsigned int)(a.w != 0) << (i * 4 + 3);
        }
        ((unsigned short*)abit)[r * 256 + tid] = (unsigned short)b;
        return;
    }

    // ---- prep branch: 4 rows/block, 256 threads (4 blocks/CU -> 4 waves/SIMD) ----
    __shared__ float srow[4][64];
    __shared__ float x1s[4][128];
    __shared__ float x2s[4][128];
    int r0 = blockIdx.x * 4;
    int c = tid & 127, g = tid >> 7;          // g = row-pair 0..1

    if (tid < 64)
        ((float4*)&srow[0][0])[tid] = ((const float4*)(state + (size_t)r0 * SDIM))[tid];
    __syncthreads();

    float acc[2];
    {   // x1 = relu(state@W1+b1)
        float bb = b1[c];
        acc[0] = bb; acc[1] = bb;
#pragma unroll 8
        for (int k = 0; k < SDIM; k++) {
            float w = W1[k * HID + c];
            acc[0] += w * srow[g * 2 + 0][k];
            acc[1] += w * srow[g * 2 + 1][k];
        }
        x1s[g * 2 + 0][c] = fmaxf(acc[0], 0.f);
        x1s[g * 2 + 1][c] = fmaxf(acc[1], 0.f);
    }
    __syncthreads();
    {   // x2 = relu(x1@W2+b2)
        float bb = b2[c];
        acc[0] = bb; acc[1] = bb;
#pragma unroll 8
        for (int k = 0; k < HID; k++) {
            float w = W2[k * HID + c];
            acc[0] += w * x1s[g * 2 + 0][k];
            acc[1] += w * x1s[g * 2 + 1][k];
        }
        x2s[g * 2 + 0][c] = fmaxf(acc[0], 0.f);
        x2s[g * 2 + 1][c] = fmaxf(acc[1], 0.f);
    }
    __syncthreads();

    int hd = c >> 5, f = c & 31;
    float hacc[2] = {0.f, 0.f};
#pragma unroll 8
    for (int k = 0; k < HID; k++) {
        float w = Wg[hd * (HID * FF) + k * FF + f];
        hacc[0] += w * x2s[g * 2 + 0][k];
        hacc[1] += w * x2s[g * 2 + 1][k];
    }

    // h^T frag order (fp16): idx(hd,f,m) =
    //   ((hd*128 + (m>>5))*2 + (f>>4))*512 + (f&15)*32 + ((m&31)>>3)*8 + (m&7)
    // m&31 = (r0&31) + g*2 + r ; r0 multiple of 4 so both halves stay in one
    // 8-m sub-block and the uint store is 4B-aligned.
    {
        int bn = f >> 4, fr = f & 15;
        int m31 = (r0 & 31) + g * 2;
        unsigned int lo = (unsigned int)__half_as_ushort(__float2half(hacc[0]));
        unsigned int hi = (unsigned int)__half_as_ushort(__float2half(hacc[1]));
        *(unsigned int*)(hTf + (size_t)((hd * 128 + (r0 >> 5)) * 2 + bn) * 512
                + fr * 32 + (m31 >> 3) * 8 + (m31 & 7)) = lo | (hi << 16);
    }

    float a1v = ag[hd * 64 + f];
    float a2v = ag[hd * 64 + 32 + f];
#pragma unroll
    for (int r = 0; r < 2; r++) {
        float p1 = hacc[r] * a1v;
        float p2 = hacc[r] * a2v;
#pragma unroll
        for (int s = 16; s >= 1; s >>= 1) {
            p1 += __shfl_xor(p1, s, 32);
            p2 += __shfl_xor(p2, s, 32);
        }
        if (f == 0) {
            s1b[hd * NN + r0 + g * 2 + r] = p1;
            s2b[hd * NN + r0 + g * 2 + r] = p2;
        }
    }
}

// ============ K2: per-head A2 + E2h/E2sh(fp16) + cpos/cneg(f32) ============
__global__ __launch_bounds__(1024) void k_headprep(
        const float* __restrict__ s1b, const float* __restrict__ s2b,
        unsigned short* __restrict__ E2h, unsigned short* __restrict__ E2sh,
        float* __restrict__ cpos, float* __restrict__ cneg) {
    int hd = blockIdx.x;
    int tid = threadIdx.x;
    __shared__ float wmax[16];

    f32x4 v2 = *(const f32x4*)(s2b + hd * NN + tid * 4);
    float m = fmaxf(fmaxf(v2[0], v2[1]), fmaxf(v2[2], v2[3]));
#pragma unroll
    for (int s = 32; s >= 1; s >>= 1) m = fmaxf(m, __shfl_xor(m, s, 64));
    if ((tid & 63) == 0) wmax[tid >> 6] = m;
    __syncthreads();
    if (tid == 0) {
        float a = wmax[0];
#pragma unroll
        for (int i = 1; i < 16; i++) a = fmaxf(a, wmax[i]);
        wmax[0] = a;
    }
    __syncthreads();
    float A2 = wmax[0];

    f32x4 v1 = *(const f32x4*)(s1b + hd * NN + tid * 4);
    us4 e2p, esp;
    f32x4 cp, cn;
#pragma unroll
    for (int i = 0; i < 4; i++) {
        e2p[i] = __half_as_ushort(__float2half(__expf(v2[i] - A2)));
        esp[i] = __half_as_ushort(__float2half(__expf(0.2f * (v2[i] - A2))));
        float u = v1[i] + A2;
        float C = fmaxf(u, 0.2f * u);
        cp[i] = __expf(u - C);
        cn[i] = __expf(0.2f * u - C);
    }
    *(us4*)(E2h + hd * NN + tid * 4) = e2p;
    *(us4*)(E2sh + hd * NN + tid * 4) = esp;
    *(f32x4*)(cpos + hd * NN + tid * 4) = cp;
    *(f32x4*)(cneg + hd * NN + tid * 4) = cn;
}

// ============ K3: attention — full-m per block, no partials ============
// w[n][m] = adj * max(cp[n]*E2[m], cn[n]*E2s[m]); out = (w-GEMM h) / (w-GEMM 1)
// block: 512 thr = 8 waves; wave w: head = w&3, m-half = w>>2 (2048 m each)
// each wave: 16 rows (am=1), 64-iter ks loop, 1-deep register prefetch.
// grid: 256 blocks (16 rows each) = 1 block/CU.
__global__ __launch_bounds__(512) void k_attn(
        const unsigned int* __restrict__ abit, const unsigned short* __restrict__ hTf,
        const unsigned short* __restrict__ E2h, const unsigned short* __restrict__ E2sh,
        const float* __restrict__ cposb, const float* __restrict__ cnegb,
        float* __restrict__ feat) {
    __shared__ unsigned int abits[16][129];   // 16 rows x 128 words, padded
    __shared__ float redacc[4][16][32];       // half-1 partial out
    __shared__ float redden[4][16];           // half-1 partial den

    int tid = threadIdx.x;
    int n0 = blockIdx.x * 16;

    {   // stage bitmask: 16 rows x 128 words, 4 words/thread
        int r = tid >> 5, q = (tid & 31) * 4;
        const unsigned int* src = abit + (size_t)(n0 + r) * 128 + q;
        abits[r][q + 0] = src[0];
        abits[r][q + 1] = src[1];
        abits[r][q + 2] = src[2];
        abits[r][q + 3] = src[3];
    }
    __syncthreads();

    int w = tid >> 6, lane = tid & 63;
    int hd = w & 3, half = w >> 2;
    int fr = lane & 15, mo = lane >> 4;
    int m0 = half * 2048;

    h2 cph, cnh;
    {
        int n = n0 + fr;
        _Float16 t1 = (_Float16)cposb[hd * NN + n];
        _Float16 t2 = (_Float16)cnegb[hd * NN + n];
        cph[0] = t1; cph[1] = t1;
        cnh[0] = t2; cnh[1] = t2;
    }

    f32x4 acc0 = (f32x4){0.f, 0.f, 0.f, 0.f};
    f32x4 acc1 = (f32x4){0.f, 0.f, 0.f, 0.f};
    f32x4 accden = (f32x4){0.f, 0.f, 0.f, 0.f};
    h8 ones;
#pragma unroll
    for (int j = 0; j < 8; j++) ones[j] = (_Float16)1.0f;

    const unsigned short* hbase = hTf + (size_t)((hd * 128 + (m0 >> 5)) * 2) * 512 + fr * 32 + mo * 8;
    const unsigned short* e2base = E2h + hd * NN + m0 + mo * 8;
    const unsigned short* esbase = E2sh + hd * NN + m0 + mo * 8;

    h8 B0c = *(const h8*)(hbase);
    h8 B1c = *(const h8*)(hbase + 512);
    uint4 e2c = *(const uint4*)(e2base);
    uint4 esc = *(const uint4*)(esbase);

#pragma unroll 2
    for (int ks = 0; ks < 64; ks++) {
        int ksn = ks < 63 ? ks + 1 : 63;
        h8 B0n = *(const h8*)(hbase + ksn * 1024);
        h8 B1n = *(const h8*)(hbase + ksn * 1024 + 512);
        uint4 e2n = *(const uint4*)(e2base + ksn * 32);
        uint4 esn = *(const uint4*)(esbase + ksn * 32);

        unsigned int bits = abits[fr][half * 64 + ks] >> (mo * 8);
        union { unsigned int u[4]; h8 v; } A;
#pragma unroll
        for (int p = 0; p < 4; p++) {
            unsigned int eu = (&e2c.x)[p], su = (&esc.x)[p];
            h2 e2h, esh;
            __builtin_memcpy(&e2h, &eu, 4);
            __builtin_memcpy(&esh, &su, 4);
            h2 w2 = h2max(cph * e2h, cnh * esh);
            unsigned int wm;
            __builtin_memcpy(&wm, &w2, 4);
            unsigned int b0 = (bits >> (2 * p)) & 1u;
            unsigned int b1 = (bits >> (2 * p + 1)) & 1u;
            wm &= ((0u - b0) & 0xFFFFu) | ((0u - b1) << 16);
            A.u[p] = wm;
        }
        acc0 = __builtin_amdgcn_mfma_f32_16x16x32_f16(A.v, B0c, acc0, 0, 0, 0);
        acc1 = __builtin_amdgcn_mfma_f32_16x16x32_f16(A.v, B1c, acc1, 0, 0, 0);
        accden = __builtin_amdgcn_mfma_f32_16x16x32_f16(A.v, ones, accden, 0, 0, 0);

        B0c = B0n; B1c = B1n; e2c = e2n; esc = esn;
    }

    // cross-half reduce: half-1 waves dump partials, half-0 waves combine.
    if (half == 1) {
#pragma unroll
        for (int r = 0; r < 4; r++) {
            redacc[hd][mo * 4 + r][fr] = acc0[r];
            redacc[hd][mo * 4 + r][16 + fr] = acc1[r];
        }
        if (fr == 0) {
#pragma unroll
            for (int r = 0; r < 4; r++) redden[hd][mo * 4 + r] = accden[r];
        }
    }
    __syncthreads();
    if (half == 0) {
#pragma unroll
        for (int r = 0; r < 4; r++) {
            int row = mo * 4 + r;
            float d = fmaxf(accden[r] + redden[hd][row], 1e-30f);
            float o0 = (acc0[r] + redacc[hd][row][fr]) / d;
            float o1 = (acc1[r] + redacc[hd][row][16 + fr]) / d;
            feat[(size_t)(n0 + row) * HID + hd * FF + fr] = o0;
            feat[(size_t)(n0 + row) * HID + hd * FF + 16 + fr] = o1;
        }
    }
}

// ============ K4: grid-partitioned policy (blocks 0..255) + value (256..511) ============
__global__ __launch_bounds__(512) void k_polval(
        const float* __restrict__ feat,
        const float* __restrict__ Wp1, const float* __restrict__ bp1,
        const float* __restrict__ Wp2, const float* __restrict__ bp2,
        const float* __restrict__ Wv1, const float* __restrict__ bv1,
        const float* __restrict__ Wv2, const float* __restrict__ bv2,
        float* __restrict__ out) {
    __shared__ float fr[16][128];
    __shared__ float hh[16][128];
    int tid = threadIdx.x;
    bool is_val = blockIdx.x >= 256;
    int r0 = (is_val ? blockIdx.x - 256 : blockIdx.x) * 16;
    const float* Wa = is_val ? Wv1 : Wp1;
    const float* ba = is_val ? bv1 : bp1;

    ((float4*)&fr[0][0])[tid] = ((const float4*)(feat + (size_t)r0 * HID))[tid];
    __syncthreads();
    int c = tid & 127, g = tid >> 7;
    float acc[4];
    float bb = ba[c];
#pragma unroll
    for (int r = 0; r < 4; r++) acc[r] = bb;
#pragma unroll 8
    for (int k = 0; k < HID; k++) {
        float w = Wa[k * HID + c];
#pragma unroll
        for (int r = 0; r < 4; r++) acc[r] += w * fr[g * 4 + r][k];
    }
#pragma unroll
    for (int r = 0; r < 4; r++) hh[g * 4 + r][c] = fmaxf(acc[r], 0.f);
    __syncthreads();

    int c2 = tid & 31, r = tid >> 5;
    if (!is_val) {
        float lacc = bp2[c2];
#pragma unroll 8
        for (int k = 0; k < HID; k++) lacc += hh[r][k] * Wp2[k * 32 + c2];
        float mx = lacc;
#pragma unroll
        for (int s = 16; s >= 1; s >>= 1) mx = fmaxf(mx, __shfl_xor(mx, s, 32));
        float e = __expf(lacc - mx);
        float sm = e;
#pragma unroll
        for (int s = 16; s >= 1; s >>= 1) sm += __shfl_xor(sm, s, 32);
        out[(size_t)(r0 + r) * 32 + c2] = e / sm;
    } else {
        float p = 0.f;
#pragma unroll
        for (int j = 0; j < 4; j++) p += hh[r][c2 + j * 32] * Wv2[c2 + j * 32];
#pragma unroll
        for (int s = 16; s >= 1; s >>= 1) p += __shfl_xor(p, s, 32);
        if (c2 == 0) out[131072 + r0 + r] = p + bv2[0];
    }
}

extern "C" void kernel_launch(void* const* d_in, const int* in_sizes, int n_in,
                              void* d_out, int out_size, void* d_ws, size_t ws_size,
                              hipStream_t stream) {
    const float* state = (const float*)d_in[0];
    const int*   adj   = (const int*)d_in[1];
    const float* W1  = (const float*)d_in[2];
    const float* b1  = (const float*)d_in[3];
    const float* W2  = (const float*)d_in[4];
    const float* b2  = (const float*)d_in[5];
    const float* Wg  = (const float*)d_in[6];
    const float* ag  = (const float*)d_in[7];
    const float* Wp1 = (const float*)d_in[8];
    const float* bp1 = (const float*)d_in[9];
    const float* Wp2 = (const float*)d_in[10];
    const float* bp2 = (const float*)d_in[11];
    const float* Wv1 = (const float*)d_in[12];
    const float* bv1 = (const float*)d_in[13];
    const float* Wv2 = (const float*)d_in[14];
    const float* bv2 = (const float*)d_in[15];
    float* out = (float*)d_out;
    float* ws = (float*)d_ws;

    unsigned short* hTf = (unsigned short*)ws;            // 524288 fp16
    float* s1b  = ws + 262144;
    float* s2b  = ws + 278528;
    unsigned short* E2h  = (unsigned short*)(ws + 294912);
    unsigned short* E2sh = (unsigned short*)(ws + 303104);
    float* cpos = ws + 311296;
    float* cneg = ws + 327680;
    unsigned int* abit = (unsigned int*)(ws + 344064);    // 2 MB
    float* feat = ws + 868352;

    hipLaunchKernelGGL(k_prep_pack, dim3(1024 + NN), dim3(256), 0, stream,
                       state, W1, b1, W2, b2, Wg, ag, adj, hTf, s1b, s2b, abit);
    hipLaunchKernelGGL(k_headprep, dim3(HEADS), dim3(1024), 0, stream,
                       s1b, s2b, E2h, E2sh, cpos, cneg);
    hipLaunchKernelGGL(k_attn, dim3(NN / 16), dim3(512), 0, stream,
                       abit, hTf, E2h, E2sh, cpos, cneg, feat);
    hipLaunchKernelGGL(k_polval, dim3(512), dim3(512), 0, stream,
                       feat, Wp1, bp1, Wp2, bp2, Wv1, bv1, Wv2, bv2, out);
}

// Round 11
// 72.511 us; speedup vs baseline: 1.1805x; 1.1805x over previous
//
#include <hip/hip_runtime.h>
#include <hip/hip_bf16.h>
#include <hip/hip_fp16.h>

#define NN 4096
#define SDIM 64
#define HID 128
#define HEADS 4
#define FF 32
#define NSPLIT 16

typedef __attribute__((ext_vector_type(8))) _Float16 h8;      // MFMA f16 A/B frag
typedef __attribute__((ext_vector_type(2))) _Float16 h2;
typedef __attribute__((ext_vector_type(4))) float f32x4;      // MFMA C/D
typedef __attribute__((ext_vector_type(4))) unsigned short us4;

__device__ inline h2 h2max(h2 a, h2 b) {
    h2 r; r[0] = a[0] > b[0] ? a[0] : b[0]; r[1] = a[1] > b[1] ? a[1] : b[1]; return r;
}

// ---------------- workspace layout (float units) ----------------
// hTf  : 0        (262144 f = 524288 fp16)  fragment-ordered h^T
// s1   : 262144   s2: 278528   (16384 each)
// E2h  : 294912   (8192 f = 16384 fp16)
// E2sh : 303104   (8192)
// cpos : 311296   cneg: 327680  (16384 each, f32)
// abit : 344064   (524288 f = 2 MB bits)
// pout : 868352   (4194304 f = 8.4M fp16)   16 splits
// pden : 5062656  (262144)
// total 5324800 floats = 21.3 MB

// ============ K1: grid-partitioned prep (blocks 0..1023, 4 rows each)
//                  + adjacency bit-pack (blocks 1024..5119, 1 row each) ============
__global__ __launch_bounds__(256) void k_prep_pack(
        const float* __restrict__ state,
        const float* __restrict__ W1, const float* __restrict__ b1,
        const float* __restrict__ W2, const float* __restrict__ b2,
        const float* __restrict__ Wg, const float* __restrict__ ag,
        const int* __restrict__ adj,
        unsigned short* __restrict__ hTf,
        float* __restrict__ s1b, float* __restrict__ s2b,
        unsigned int* __restrict__ abit) {
    int tid = threadIdx.x;

    if (blockIdx.x >= 1024) {
        // ---- pack branch: thread t packs 16 ints -> ushort ----
        int r = blockIdx.x - 1024;
        const int4* ap = (const int4*)(adj + (size_t)r * NN + tid * 16);
        unsigned int b = 0;
#pragma unroll
        for (int i = 0; i < 4; i++) {
            int4 a = ap[i];
            b |= (unsigned int)(a.x != 0) << (i * 4 + 0);
            b |= (unsigned int)(a.y != 0) << (i * 4 + 1);
            b |= (unsigned int)(a.z != 0) << (i * 4 + 2);
            b |= (unsigned int)(a.w != 0) << (i * 4 + 3);
        }
        ((unsigned short*)abit)[r * 256 + tid] = (unsigned short)b;
        return;
    }

    // ---- prep branch: 4 rows/block, 256 threads ----
    __shared__ float srow[4][64];
    __shared__ float x1s[4][128];
    __shared__ float x2s[4][128];
    int r0 = blockIdx.x * 4;
    int c = tid & 127, g = tid >> 7;          // g = row-pair 0..1

    if (tid < 64)
        ((float4*)&srow[0][0])[tid] = ((const float4*)(state + (size_t)r0 * SDIM))[tid];
    __syncthreads();

    float acc[2];
    {   // x1 = relu(state@W1+b1)
        float bb = b1[c];
        acc[0] = bb; acc[1] = bb;
#pragma unroll 8
        for (int k = 0; k < SDIM; k++) {
            float w = W1[k * HID + c];
            acc[0] += w * srow[g * 2 + 0][k];
            acc[1] += w * srow[g * 2 + 1][k];
        }
        x1s[g * 2 + 0][c] = fmaxf(acc[0], 0.f);
        x1s[g * 2 + 1][c] = fmaxf(acc[1], 0.f);
    }
    __syncthreads();
    {   // x2 = relu(x1@W2+b2)
        float bb = b2[c];
        acc[0] = bb; acc[1] = bb;
#pragma unroll 8
        for (int k = 0; k < HID; k++) {
            float w = W2[k * HID + c];
            acc[0] += w * x1s[g * 2 + 0][k];
            acc[1] += w * x1s[g * 2 + 1][k];
        }
        x2s[g * 2 + 0][c] = fmaxf(acc[0], 0.f);
        x2s[g * 2 + 1][c] = fmaxf(acc[1], 0.f);
    }
    __syncthreads();

    int hd = c >> 5, f = c & 31;
    float hacc[2] = {0.f, 0.f};
#pragma unroll 8
    for (int k = 0; k < HID; k++) {
        float w = Wg[hd * (HID * FF) + k * FF + f];
        hacc[0] += w * x2s[g * 2 + 0][k];
        hacc[1] += w * x2s[g * 2 + 1][k];
    }

    // h^T frag order (fp16): idx(hd,f,m) =
    //   ((hd*128 + (m>>5))*2 + (f>>4))*512 + (f&15)*32 + ((m&31)>>3)*8 + (m&7)
    {
        int bn = f >> 4, fr = f & 15;
        int m31 = (r0 & 31) + g * 2;
        unsigned int lo = (unsigned int)__half_as_ushort(__float2half(hacc[0]));
        unsigned int hi = (unsigned int)__half_as_ushort(__float2half(hacc[1]));
        *(unsigned int*)(hTf + (size_t)((hd * 128 + (r0 >> 5)) * 2 + bn) * 512
                + fr * 32 + (m31 >> 3) * 8 + (m31 & 7)) = lo | (hi << 16);
    }

    float a1v = ag[hd * 64 + f];
    float a2v = ag[hd * 64 + 32 + f];
#pragma unroll
    for (int r = 0; r < 2; r++) {
        float p1 = hacc[r] * a1v;
        float p2 = hacc[r] * a2v;
#pragma unroll
        for (int s = 16; s >= 1; s >>= 1) {
            p1 += __shfl_xor(p1, s, 32);
            p2 += __shfl_xor(p2, s, 32);
        }
        if (f == 0) {
            s1b[hd * NN + r0 + g * 2 + r] = p1;
            s2b[hd * NN + r0 + g * 2 + r] = p2;
        }
    }
}

// ============ K2: per-head A2 + E2h/E2sh(fp16) + cpos/cneg(f32) ============
__global__ __launch_bounds__(1024) void k_headprep(
        const float* __restrict__ s1b, const float* __restrict__ s2b,
        unsigned short* __restrict__ E2h, unsigned short* __restrict__ E2sh,
        float* __restrict__ cpos, float* __restrict__ cneg) {
    int hd = blockIdx.x;
    int tid = threadIdx.x;
    __shared__ float wmax[16];

    f32x4 v2 = *(const f32x4*)(s2b + hd * NN + tid * 4);
    float m = fmaxf(fmaxf(v2[0], v2[1]), fmaxf(v2[2], v2[3]));
#pragma unroll
    for (int s = 32; s >= 1; s >>= 1) m = fmaxf(m, __shfl_xor(m, s, 64));
    if ((tid & 63) == 0) wmax[tid >> 6] = m;
    __syncthreads();
    if (tid == 0) {
        float a = wmax[0];
#pragma unroll
        for (int i = 1; i < 16; i++) a = fmaxf(a, wmax[i]);
        wmax[0] = a;
    }
    __syncthreads();
    float A2 = wmax[0];

    f32x4 v1 = *(const f32x4*)(s1b + hd * NN + tid * 4);
    us4 e2p, esp;
    f32x4 cp, cn;
#pragma unroll
    for (int i = 0; i < 4; i++) {
        e2p[i] = __half_as_ushort(__float2half(__expf(v2[i] - A2)));
        esp[i] = __half_as_ushort(__float2half(__expf(0.2f * (v2[i] - A2))));
        float u = v1[i] + A2;
        float C = fmaxf(u, 0.2f * u);
        cp[i] = __expf(u - C);
        cn[i] = __expf(0.2f * u - C);
    }
    *(us4*)(E2h + hd * NN + tid * 4) = e2p;
    *(us4*)(E2sh + hd * NN + tid * 4) = esp;
    *(f32x4*)(cpos + hd * NN + tid * 4) = cp;
    *(f32x4*)(cneg + hd * NN + tid * 4) = cn;
}

// ============ K3: attention — head-major, fully LDS-resident inner loop ============
// block: one head x 256 rows x 256 m; 256 thr = 4 waves (wave = 64-row band)
// grid: 16 row-tiles * 16 splits * 4 heads = 1024 blocks (4/CU, 16 waves/CU)
__global__ __launch_bounds__(256, 4) void k_attn(
        const unsigned int* __restrict__ abit, const unsigned short* __restrict__ hTf,
        const unsigned short* __restrict__ E2h, const unsigned short* __restrict__ E2sh,
        const float* __restrict__ cposb, const float* __restrict__ cnegb,
        __half* __restrict__ pout, float* __restrict__ pden) {
    __shared__ unsigned short hTl[8192];      // 16 KB, [ks][bn][lane] lane-linear frags
    __shared__ unsigned int abits[256][9];    // 256 rows x 8 words, padded
    __shared__ unsigned short e2l[256];       // fp16 E2 for this head's m-chunk
    __shared__ unsigned short esl[256];       // fp16 E2s

    int tid = threadIdx.x;
    int tile = blockIdx.x & 15;
    int split = (blockIdx.x >> 4) & 15;
    int hd = blockIdx.x >> 8;
    int nb = tile * 256, m0 = split * 256;

    {   // stage hT tile: 1024 frags (uint4), permuted src -> lane-linear LDS
#pragma unroll
        for (int i = 0; i < 4; i++) {
            int li = tid + i * 256;                     // (ks*2+bn)*64 + lane
            int lane2 = li & 63;
            int fr2 = lane2 & 15, mo2 = lane2 >> 4;
            int ksbn = li >> 6;                          // ks*2+bn
            const unsigned short* src = hTf
                + (size_t)((hd * 256 + (m0 >> 5) * 2) + ((ksbn >> 1) * 2 + (ksbn & 1))) * 512
                + fr2 * 32 + mo2 * 8;
            *(uint4*)&hTl[li * 8] = *(const uint4*)src;
        }
    }
    {   // stage adjacency: row t, 8 words
        const unsigned int* src = abit + (size_t)(nb + tid) * 128 + split * 8;
        *(uint4*)&abits[tid][0] = *(const uint4*)src;
        *(uint4*)&abits[tid][4] = *(const uint4*)(src + 4);
    }
    if (tid < 32) {          // stage E2 (256 halves)
        *(uint4*)&e2l[tid * 8] = *(const uint4*)(E2h + hd * NN + m0 + tid * 8);
    } else if (tid < 64) {   // stage E2s
        int t = tid - 32;
        *(uint4*)&esl[t * 8] = *(const uint4*)(E2sh + hd * NN + m0 + t * 8);
    }
    __syncthreads();

    int w = tid >> 6, lane = tid & 63;
    int fr = lane & 15, mo = lane >> 4;
    int nw0 = nb + w * 64;

    h2 cph[4], cnh[4];
#pragma unroll
    for (int am = 0; am < 4; am++) {
        int n = nw0 + am * 16 + fr;
        _Float16 t1 = (_Float16)cposb[hd * NN + n];
        _Float16 t2 = (_Float16)cnegb[hd * NN + n];
        cph[am][0] = t1; cph[am][1] = t1;
        cnh[am][0] = t2; cnh[am][1] = t2;
    }

    f32x4 acc[4][2];
    f32x4 accden[4];
#pragma unroll
    for (int am = 0; am < 4; am++) {
#pragma unroll
        for (int bn = 0; bn < 2; bn++) acc[am][bn] = (f32x4){0.f, 0.f, 0.f, 0.f};
        accden[am] = (f32x4){0.f, 0.f, 0.f, 0.f};
    }

    h8 ones;
#pragma unroll
    for (int j = 0; j < 8; j++) ones[j] = (_Float16)1.0f;

#pragma unroll 2
    for (int ks = 0; ks < 8; ks++) {
        h8 B0 = *(const h8*)&hTl[(ks * 2 + 0) * 512 + lane * 8];
        h8 B1 = *(const h8*)&hTl[(ks * 2 + 1) * 512 + lane * 8];
        uint4 e2v = *(const uint4*)&e2l[ks * 32 + mo * 8];
        uint4 esv = *(const uint4*)&esl[ks * 32 + mo * 8];

#pragma unroll
        for (int am = 0; am < 4; am++) {
            unsigned int bits = abits[w * 64 + am * 16 + fr][ks] >> (mo * 8);
            union { unsigned int u[4]; h8 v; } A;
#pragma unroll
            for (int p = 0; p < 4; p++) {
                unsigned int eu = (&e2v.x)[p], su = (&esv.x)[p];
                h2 e2h, esh;
                __builtin_memcpy(&e2h, &eu, 4);
                __builtin_memcpy(&esh, &su, 4);
                h2 w2 = h2max(cph[am] * e2h, cnh[am] * esh);
                unsigned int wm;
                __builtin_memcpy(&wm, &w2, 4);
                unsigned int b0 = (bits >> (2 * p)) & 1u;
                unsigned int b1 = (bits >> (2 * p + 1)) & 1u;
                wm &= ((0u - b0) & 0xFFFFu) | ((0u - b1) << 16);
                A.u[p] = wm;
            }
            acc[am][0] = __builtin_amdgcn_mfma_f32_16x16x32_f16(A.v, B0, acc[am][0], 0, 0, 0);
            acc[am][1] = __builtin_amdgcn_mfma_f32_16x16x32_f16(A.v, B1, acc[am][1], 0, 0, 0);
            accden[am] = __builtin_amdgcn_mfma_f32_16x16x32_f16(A.v, ones, accden[am], 0, 0, 0);
        }
    }

    __half* pob = pout + ((size_t)(split * 4 + hd) * NN + nw0) * FF;
#pragma unroll
    for (int am = 0; am < 4; am++) {
#pragma unroll
        for (int bn = 0; bn < 2; bn++) {
            f32x4 cv = acc[am][bn];
#pragma unroll
            for (int r = 0; r < 4; r++)
                pob[(am * 16 + mo * 4 + r) * FF + bn * 16 + fr] = __float2half(cv[r]);
        }
        // accden D-layout: row = mo*4+r, col = fr (all cols equal rowsum)
        if (fr == 0) {
#pragma unroll
            for (int r = 0; r < 4; r++)
                pden[(size_t)(split * 4 + hd) * NN + nw0 + am * 16 + mo * 4 + r] = accden[am][r];
        }
    }
}

// ============ K4: fused reduce + policy + value (256 blocks x 512 thr) ============
__global__ __launch_bounds__(512) void k_redpolval(
        const __half* __restrict__ pout, const float* __restrict__ pden,
        const float* __restrict__ Wp1, const float* __restrict__ bp1,
        const float* __restrict__ Wp2, const float* __restrict__ bp2,
        const float* __restrict__ Wv1, const float* __restrict__ bv1,
        const float* __restrict__ Wv2, const float* __restrict__ bv2,
        float* __restrict__ out) {
    __shared__ float fr[16][128];
    __shared__ float hh[16][128];
    __shared__ float dens[16][4];
    int tid = threadIdx.x;
    int r0 = blockIdx.x * 16;

    // ---- phase 1: den[n][hd] = sum over 16 splits ----
    {
        int p = tid >> 3, sg = tid & 7;     // p = r*4+hd
        int r = p >> 2, hd = p & 3;
        float d = 0.f;
#pragma unroll
        for (int i = 0; i < NSPLIT / 8; i++)
            d += pden[(size_t)((sg + i * 8) * 4 + hd) * NN + r0 + r];
#pragma unroll
        for (int s = 4; s >= 1; s >>= 1) d += __shfl_xor(d, s, 8);
        if (sg == 0) dens[r][hd] = d;
    }

    // ---- phase 2: feat = (sum of fp16 partials) / den ----
    int row = tid >> 5, c4 = (tid & 31) * 4;
    int hd2 = c4 >> 5;
    float o4[4] = {0.f, 0.f, 0.f, 0.f};
    const __half* pp = pout + ((size_t)hd2 * NN + r0 + row) * 32 + (c4 & 31);
#pragma unroll
    for (int s = 0; s < NSPLIT; s++) {
        float2 raw = *(const float2*)(pp + (size_t)s * 4 * NN * 32);
        __half2 ha = *(__half2*)&raw.x;
        __half2 hb = *(__half2*)&raw.y;
        float2 fa = __half22float2(ha), fb = __half22float2(hb);
        o4[0] += fa.x; o4[1] += fa.y; o4[2] += fb.x; o4[3] += fb.y;
    }
    __syncthreads();
    {
        float dn = fmaxf(dens[row][hd2], 1e-30f);
#pragma unroll
        for (int i = 0; i < 4; i++) fr[row][c4 + i] = o4[i] / dn;
    }
    __syncthreads();

    int c = tid & 127, g = tid >> 7;
    int c2 = tid & 31, r = tid >> 5;

    // ---- phase 3a: policy hidden ----
    {
        float acc[4];
        float bb = bp1[c];
#pragma unroll
        for (int q = 0; q < 4; q++) acc[q] = bb;
#pragma unroll 8
        for (int k = 0; k < HID; k++) {
            float w = Wp1[k * HID + c];
#pragma unroll
            for (int q = 0; q < 4; q++) acc[q] += w * fr[g * 4 + q][k];
        }
#pragma unroll
        for (int q = 0; q < 4; q++) hh[g * 4 + q][c] = fmaxf(acc[q], 0.f);
    }
    __syncthreads();
    {   // policy out + softmax
        float lacc = bp2[c2];
#pragma unroll 8
        for (int k = 0; k < HID; k++) lacc += hh[r][k] * Wp2[k * 32 + c2];
        float mx = lacc;
#pragma unroll
        for (int s = 16; s >= 1; s >>= 1) mx = fmaxf(mx, __shfl_xor(mx, s, 32));
        float e = __expf(lacc - mx);
        float sm = e;
#pragma unroll
        for (int s = 16; s >= 1; s >>= 1) sm += __shfl_xor(sm, s, 32);
        out[(size_t)(r0 + r) * 32 + c2] = e / sm;
    }
    __syncthreads();

    // ---- phase 3b: value hidden (reuse hh) ----
    {
        float acc[4];
        float bb = bv1[c];
#pragma unroll
        for (int q = 0; q < 4; q++) acc[q] = bb;
#pragma unroll 8
        for (int k = 0; k < HID; k++) {
            float w = Wv1[k * HID + c];
#pragma unroll
            for (int q = 0; q < 4; q++) acc[q] += w * fr[g * 4 + q][k];
        }
#pragma unroll
        for (int q = 0; q < 4; q++) hh[g * 4 + q][c] = fmaxf(acc[q], 0.f);
    }
    __syncthreads();
    {   // value out
        float p = 0.f;
#pragma unroll
        for (int j = 0; j < 4; j++) p += hh[r][c2 + j * 32] * Wv2[c2 + j * 32];
#pragma unroll
        for (int s = 16; s >= 1; s >>= 1) p += __shfl_xor(p, s, 32);
        if (c2 == 0) out[131072 + r0 + r] = p + bv2[0];
    }
}

extern "C" void kernel_launch(void* const* d_in, const int* in_sizes, int n_in,
                              void* d_out, int out_size, void* d_ws, size_t ws_size,
                              hipStream_t stream) {
    const float* state = (const float*)d_in[0];
    const int*   adj   = (const int*)d_in[1];
    const float* W1  = (const float*)d_in[2];
    const float* b1  = (const float*)d_in[3];
    const float* W2  = (const float*)d_in[4];
    const float* b2  = (const float*)d_in[5];
    const float* Wg  = (const float*)d_in[6];
    const float* ag  = (const float*)d_in[7];
    const float* Wp1 = (const float*)d_in[8];
    const float* bp1 = (const float*)d_in[9];
    const float* Wp2 = (const float*)d_in[10];
    const float* bp2 = (const float*)d_in[11];
    const float* Wv1 = (const float*)d_in[12];
    const float* bv1 = (const float*)d_in[13];
    const float* Wv2 = (const float*)d_in[14];
    const float* bv2 = (const float*)d_in[15];
    float* out = (float*)d_out;
    float* ws = (float*)d_ws;

    unsigned short* hTf = (unsigned short*)ws;            // 524288 fp16
    float* s1b  = ws + 262144;
    float* s2b  = ws + 278528;
    unsigned short* E2h  = (unsigned short*)(ws + 294912);
    unsigned short* E2sh = (unsigned short*)(ws + 303104);
    float* cpos = ws + 311296;
    float* cneg = ws + 327680;
    unsigned int* abit = (unsigned int*)(ws + 344064);    // 2 MB
    __half* pout = (__half*)(ws + 868352);                // 8.4M fp16
    float* pden = ws + 5062656;

    hipLaunchKernelGGL(k_prep_pack, dim3(1024 + NN), dim3(256), 0, stream,
                       state, W1, b1, W2, b2, Wg, ag, adj, hTf, s1b, s2b, abit);
    hipLaunchKernelGGL(k_headprep, dim3(HEADS), dim3(1024), 0, stream,
                       s1b, s2b, E2h, E2sh, cpos, cneg);
    hipLaunchKernelGGL(k_attn, dim3(16 * 16 * HEADS), dim3(256), 0, stream,
                       abit, hTf, E2h, E2sh, cpos, cneg, pout, pden);
    hipLaunchKernelGGL(k_redpolval, dim3(NN / 16), dim3(512), 0, stream,
                       pout, pden, Wp1, bp1, Wp2, bp2, Wv1, bv1, Wv2, bv2, out);
}

// Round 12
// 65.390 us; speedup vs baseline: 1.3090x; 1.1089x over previous
//
#include <hip/hip_runtime.h>
#include <hip/hip_bf16.h>
#include <hip/hip_fp16.h>

#define NN 4096
#define SDIM 64
#define HID 128
#define HEADS 4
#define FF 32
#define NSPLIT 8

typedef __attribute__((ext_vector_type(8))) _Float16 h8;      // MFMA f16 A/B frag
typedef __attribute__((ext_vector_type(2))) _Float16 h2;
typedef __attribute__((ext_vector_type(4))) float f32x4;      // MFMA C/D
typedef __attribute__((ext_vector_type(4))) unsigned short us4;

__device__ inline h2 h2max(h2 a, h2 b) {
    h2 r; r[0] = a[0] > b[0] ? a[0] : b[0]; r[1] = a[1] > b[1] ? a[1] : b[1]; return r;
}

// ---------------- workspace layout (float units) ----------------
// hTf  : 0        (262144 f = 524288 fp16)  fragment-ordered h^T
// s1   : 262144   s2: 278528   (16384 each)
// E2h  : 294912   (8192 f = 16384 fp16)
// E2sh : 303104   (8192)
// cpos : 311296   cneg: 327680  (16384 each, f32)
// abit : 344064   (524288 f = 2 MB bits)
// pout : 868352   (2097152 f = 4.2M fp16)   8 splits
// pden : 2965504  (131072)
// total 3096576 floats = 12.4 MB

// ============ K1: grid-partitioned prep (blocks 0..511, 8 rows each, LDS-staged W)
//                  + adjacency bit-pack (blocks 512..4607, 1 row each) ============
__global__ __launch_bounds__(256) void k_prep_pack(
        const float* __restrict__ state,
        const float* __restrict__ W1, const float* __restrict__ b1,
        const float* __restrict__ W2, const float* __restrict__ b2,
        const float* __restrict__ Wg, const float* __restrict__ ag,
        const int* __restrict__ adj,
        unsigned short* __restrict__ hTf,
        float* __restrict__ s1b, float* __restrict__ s2b,
        unsigned int* __restrict__ abit) {
    int tid = threadIdx.x;

    if (blockIdx.x >= 512) {
        // ---- pack branch: thread t packs 16 ints -> ushort ----
        int r = blockIdx.x - 512;
        const int4* ap = (const int4*)(adj + (size_t)r * NN + tid * 16);
        unsigned int b = 0;
#pragma unroll
        for (int i = 0; i < 4; i++) {
            int4 a = ap[i];
            b |= (unsigned int)(a.x != 0) << (i * 4 + 0);
            b |= (unsigned int)(a.y != 0) << (i * 4 + 1);
            b |= (unsigned int)(a.z != 0) << (i * 4 + 2);
            b |= (unsigned int)(a.w != 0) << (i * 4 + 3);
        }
        ((unsigned short*)abit)[r * 256 + tid] = (unsigned short)b;
        return;
    }

    // ---- prep branch: 8 rows/block, 256 threads, weights staged in LDS ----
    __shared__ float wbuf[8192];      // 32 KB staging (W1 | W2-half | Wg-half)
    __shared__ float srow[8][64];
    __shared__ float x1s[8][128];
    __shared__ float x2s[8][128];
    int r0 = blockIdx.x * 8;
    int c = tid & 127, g = tid >> 7;          // g = row-quad 0..1

    // stage state rows + W1 (8192 floats, coalesced float4)
    if (tid < 128)
        ((float4*)&srow[0][0])[tid] = ((const float4*)(state + (size_t)r0 * SDIM))[tid];
#pragma unroll
    for (int i = 0; i < 8; i++)
        ((float4*)wbuf)[tid + i * 256] = ((const float4*)W1)[tid + i * 256];
    __syncthreads();

    float acc[4];
    {   // x1 = relu(state@W1+b1), W1 from LDS
        float bb = b1[c];
#pragma unroll
        for (int r = 0; r < 4; r++) acc[r] = bb;
#pragma unroll 8
        for (int k = 0; k < SDIM; k++) {
            float w = wbuf[k * HID + c];
#pragma unroll
            for (int r = 0; r < 4; r++) acc[r] += w * srow[g * 4 + r][k];
        }
#pragma unroll
        for (int r = 0; r < 4; r++) x1s[g * 4 + r][c] = fmaxf(acc[r], 0.f);
    }

    {   // x2 = relu(x1@W2+b2), W2 staged in two 32 KB halves
        float bb = b2[c];
#pragma unroll
        for (int r = 0; r < 4; r++) acc[r] = bb;
#pragma unroll
        for (int hh = 0; hh < 2; hh++) {
            __syncthreads();
#pragma unroll
            for (int i = 0; i < 8; i++)
                ((float4*)wbuf)[tid + i * 256] = ((const float4*)(W2 + hh * 8192))[tid + i * 256];
            __syncthreads();
#pragma unroll 8
            for (int k = 0; k < 64; k++) {
                float w = wbuf[k * HID + c];
#pragma unroll
                for (int r = 0; r < 4; r++) acc[r] += w * x1s[g * 4 + r][hh * 64 + k];
            }
        }
#pragma unroll
        for (int r = 0; r < 4; r++) x2s[g * 4 + r][c] = fmaxf(acc[r], 0.f);
    }

    int hd = c >> 5, f = c & 31;
    float hacc[4];
#pragma unroll
    for (int r = 0; r < 4; r++) hacc[r] = 0.f;
    {   // h = x2 @ Wg, Wg staged in two halves; LDS index k*128 + hd*32 + f
#pragma unroll
        for (int hh = 0; hh < 2; hh++) {
            __syncthreads();
#pragma unroll
            for (int i = 0; i < 32; i++) {
                int L = tid + i * 256;
                int kk = L >> 7, cc = L & 127;
                wbuf[L] = Wg[(cc >> 5) * (HID * FF) + (hh * 64 + kk) * FF + (cc & 31)];
            }
            __syncthreads();
#pragma unroll 8
            for (int k = 0; k < 64; k++) {
                float w = wbuf[k * HID + c];
#pragma unroll
                for (int r = 0; r < 4; r++) hacc[r] += w * x2s[g * 4 + r][hh * 64 + k];
            }
        }
    }

    // h^T frag order (fp16): idx(hd,f,m) =
    //   ((hd*128 + (m>>5))*2 + (f>>4))*512 + (f&15)*32 + ((m&31)>>3)*8 + (m&7)
    {
        int bn = f >> 4, fr = f & 15;
        int m31 = (r0 & 31) + g * 4;
        us4 pk;
#pragma unroll
        for (int r = 0; r < 4; r++) pk[r] = __half_as_ushort(__float2half(hacc[r]));
        *(us4*)(hTf + (size_t)((hd * 128 + (r0 >> 5)) * 2 + bn) * 512
                + fr * 32 + (m31 >> 3) * 8 + (m31 & 7)) = pk;
    }

    float a1v = ag[hd * 64 + f];
    float a2v = ag[hd * 64 + 32 + f];
#pragma unroll
    for (int r = 0; r < 4; r++) {
        float p1 = hacc[r] * a1v;
        float p2 = hacc[r] * a2v;
#pragma unroll
        for (int s = 16; s >= 1; s >>= 1) {
            p1 += __shfl_xor(p1, s, 32);
            p2 += __shfl_xor(p2, s, 32);
        }
        if (f == 0) {
            s1b[hd * NN + r0 + g * 4 + r] = p1;
            s2b[hd * NN + r0 + g * 4 + r] = p2;
        }
    }
}

// ============ K2: per-head A2 + E2h/E2sh(fp16) + cpos/cneg(f32) ============
__global__ __launch_bounds__(1024) void k_headprep(
        const float* __restrict__ s1b, const float* __restrict__ s2b,
        unsigned short* __restrict__ E2h, unsigned short* __restrict__ E2sh,
        float* __restrict__ cpos, float* __restrict__ cneg) {
    int hd = blockIdx.x;
    int tid = threadIdx.x;
    __shared__ float wmax[16];

    f32x4 v2 = *(const f32x4*)(s2b + hd * NN + tid * 4);
    float m = fmaxf(fmaxf(v2[0], v2[1]), fmaxf(v2[2], v2[3]));
#pragma unroll
    for (int s = 32; s >= 1; s >>= 1) m = fmaxf(m, __shfl_xor(m, s, 64));
    if ((tid & 63) == 0) wmax[tid >> 6] = m;
    __syncthreads();
    if (tid == 0) {
        float a = wmax[0];
#pragma unroll
        for (int i = 1; i < 16; i++) a = fmaxf(a, wmax[i]);
        wmax[0] = a;
    }
    __syncthreads();
    float A2 = wmax[0];

    f32x4 v1 = *(const f32x4*)(s1b + hd * NN + tid * 4);
    us4 e2p, esp;
    f32x4 cp, cn;
#pragma unroll
    for (int i = 0; i < 4; i++) {
        e2p[i] = __half_as_ushort(__float2half(__expf(v2[i] - A2)));
        esp[i] = __half_as_ushort(__float2half(__expf(0.2f * (v2[i] - A2))));
        float u = v1[i] + A2;
        float C = fmaxf(u, 0.2f * u);
        cp[i] = __expf(u - C);
        cn[i] = __expf(0.2f * u - C);
    }
    *(us4*)(E2h + hd * NN + tid * 4) = e2p;
    *(us4*)(E2sh + hd * NN + tid * 4) = esp;
    *(f32x4*)(cpos + hd * NN + tid * 4) = cp;
    *(f32x4*)(cneg + hd * NN + tid * 4) = cn;
}

// ============ K3: attention — head-major, fully LDS-resident inner loop ============
// block: one head x 128 rows x 512 m; 256 thr = 4 waves (wave = 32-row band)
// grid: 32 row-tiles * 8 splits * 4 heads = 1024 blocks (LDS 43KB -> 3/CU)
__global__ __launch_bounds__(256, 4) void k_attn(
        const unsigned int* __restrict__ abit, const unsigned short* __restrict__ hTf,
        const unsigned short* __restrict__ E2h, const unsigned short* __restrict__ E2sh,
        const float* __restrict__ cposb, const float* __restrict__ cnegb,
        __half* __restrict__ pout, float* __restrict__ pden) {
    __shared__ unsigned short hTl[16384];     // 32 KB, [ks*2+bn][lane] lane-linear frags
    __shared__ unsigned int abits[128][17];   // 128 rows x 16 words, padded
    __shared__ unsigned short e2l[512];       // fp16 E2 for this head's m-chunk
    __shared__ unsigned short esl[512];       // fp16 E2s

    int tid = threadIdx.x;
    int tile = blockIdx.x & 31;
    int split = (blockIdx.x >> 5) & 7;
    int hd = blockIdx.x >> 8;
    int nb = tile * 128, m0 = split * 512;

    {   // stage hT tile: 2048 frags (uint4), permuted src -> lane-linear LDS
#pragma unroll
        for (int i = 0; i < 8; i++) {
            int li = tid + i * 256;                     // (fb*2+bn)*64 + lane
            int lane2 = li & 63;
            int fr2 = lane2 & 15, mo2 = lane2 >> 4;
            int ksbn = li >> 6;                          // fb*2+bn
            const unsigned short* src = hTf
                + (size_t)((hd * 128 + (m0 >> 5) + (ksbn >> 1)) * 2 + (ksbn & 1)) * 512
                + fr2 * 32 + mo2 * 8;
            *(uint4*)&hTl[li * 8] = *(const uint4*)src;
        }
    }
    {   // stage adjacency: 128 rows x 16 words (2 uint4 per thread)
        int r = tid >> 1, q = (tid & 1) * 8;
        const unsigned int* src = abit + (size_t)(nb + r) * 128 + split * 16 + q;
        *(uint4*)&abits[r][q] = *(const uint4*)src;
        *(uint4*)&abits[r][q + 4] = *(const uint4*)(src + 4);
    }
    if (tid < 64) {          // stage E2 (512 halves)
        *(uint4*)&e2l[tid * 8] = *(const uint4*)(E2h + hd * NN + m0 + tid * 8);
    } else if (tid < 128) {  // stage E2s
        int t = tid - 64;
        *(uint4*)&esl[t * 8] = *(const uint4*)(E2sh + hd * NN + m0 + t * 8);
    }
    __syncthreads();

    int w = tid >> 6, lane = tid & 63;
    int fr = lane & 15, mo = lane >> 4;
    int nw0 = nb + w * 32;

    h2 cph[2], cnh[2];
#pragma unroll
    for (int am = 0; am < 2; am++) {
        int n = nw0 + am * 16 + fr;
        _Float16 t1 = (_Float16)cposb[hd * NN + n];
        _Float16 t2 = (_Float16)cnegb[hd * NN + n];
        cph[am][0] = t1; cph[am][1] = t1;
        cnh[am][0] = t2; cnh[am][1] = t2;
    }

    f32x4 acc[2][2];
    f32x4 accden[2];
#pragma unroll
    for (int am = 0; am < 2; am++) {
#pragma unroll
        for (int bn = 0; bn < 2; bn++) acc[am][bn] = (f32x4){0.f, 0.f, 0.f, 0.f};
        accden[am] = (f32x4){0.f, 0.f, 0.f, 0.f};
    }

    h8 ones;
#pragma unroll
    for (int j = 0; j < 8; j++) ones[j] = (_Float16)1.0f;

#pragma unroll 2
    for (int ks = 0; ks < 16; ks++) {
        h8 B0 = *(const h8*)&hTl[(ks * 2 + 0) * 512 + lane * 8];
        h8 B1 = *(const h8*)&hTl[(ks * 2 + 1) * 512 + lane * 8];
        uint4 e2v = *(const uint4*)&e2l[ks * 32 + mo * 8];
        uint4 esv = *(const uint4*)&esl[ks * 32 + mo * 8];

#pragma unroll
        for (int am = 0; am < 2; am++) {
            unsigned int bits = abits[w * 32 + am * 16 + fr][ks] >> (mo * 8);
            union { unsigned int u[4]; h8 v; } A;
#pragma unroll
            for (int p = 0; p < 4; p++) {
                unsigned int eu = (&e2v.x)[p], su = (&esv.x)[p];
                h2 e2h, esh;
                __builtin_memcpy(&e2h, &eu, 4);
                __builtin_memcpy(&esh, &su, 4);
                h2 w2 = h2max(cph[am] * e2h, cnh[am] * esh);
                unsigned int wm;
                __builtin_memcpy(&wm, &w2, 4);
                unsigned int b0 = (bits >> (2 * p)) & 1u;
                unsigned int b1 = (bits >> (2 * p + 1)) & 1u;
                wm &= ((0u - b0) & 0xFFFFu) | ((0u - b1) << 16);
                A.u[p] = wm;
            }
            acc[am][0] = __builtin_amdgcn_mfma_f32_16x16x32_f16(A.v, B0, acc[am][0], 0, 0, 0);
            acc[am][1] = __builtin_amdgcn_mfma_f32_16x16x32_f16(A.v, B1, acc[am][1], 0, 0, 0);
            accden[am] = __builtin_amdgcn_mfma_f32_16x16x32_f16(A.v, ones, accden[am], 0, 0, 0);
        }
    }

    __half* pob = pout + ((size_t)(split * 4 + hd) * NN + nw0) * FF;
#pragma unroll
    for (int am = 0; am < 2; am++) {
#pragma unroll
        for (int bn = 0; bn < 2; bn++) {
            f32x4 cv = acc[am][bn];
#pragma unroll
            for (int r = 0; r < 4; r++)
                pob[(am * 16 + mo * 4 + r) * FF + bn * 16 + fr] = __float2half(cv[r]);
        }
        // accden D-layout: row = mo*4+r, col = fr (all cols equal rowsum)
        if (fr == 0) {
#pragma unroll
            for (int r = 0; r < 4; r++)
                pden[(size_t)(split * 4 + hd) * NN + nw0 + am * 16 + mo * 4 + r] = accden[am][r];
        }
    }
}

// ============ K4: fused reduce + policy + value (256 blocks x 512 thr) ============
__global__ __launch_bounds__(512) void k_redpolval(
        const __half* __restrict__ pout, const float* __restrict__ pden,
        const float* __restrict__ Wp1, const float* __restrict__ bp1,
        const float* __restrict__ Wp2, const float* __restrict__ bp2,
        const float* __restrict__ Wv1, const float* __restrict__ bv1,
        const float* __restrict__ Wv2, const float* __restrict__ bv2,
        float* __restrict__ out) {
    __shared__ float fr[16][128];
    __shared__ float hh[16][128];
    __shared__ float dens[16][4];
    int tid = threadIdx.x;
    int r0 = blockIdx.x * 16;

    // ---- phase 1: den[n][hd] = sum over 8 splits ----
    {
        int p = tid >> 3, sg = tid & 7;     // p = r*4+hd
        int r = p >> 2, hd = p & 3;
        float d = pden[(size_t)(sg * 4 + hd) * NN + r0 + r];
#pragma unroll
        for (int s = 4; s >= 1; s >>= 1) d += __shfl_xor(d, s, 8);
        if (sg == 0) dens[r][hd] = d;
    }

    // ---- phase 2: feat = (sum of fp16 partials) / den ----
    int row = tid >> 5, c4 = (tid & 31) * 4;
    int hd2 = c4 >> 5;
    float o4[4] = {0.f, 0.f, 0.f, 0.f};
    const __half* pp = pout + ((size_t)hd2 * NN + r0 + row) * 32 + (c4 & 31);
#pragma unroll
    for (int s = 0; s < NSPLIT; s++) {
        float2 raw = *(const float2*)(pp + (size_t)s * 4 * NN * 32);
        __half2 ha = *(__half2*)&raw.x;
        __half2 hb = *(__half2*)&raw.y;
        float2 fa = __half22float2(ha), fb = __half22float2(hb);
        o4[0] += fa.x; o4[1] += fa.y; o4[2] += fb.x; o4[3] += fb.y;
    }
    __syncthreads();
    {
        float dn = fmaxf(dens[row][hd2], 1e-30f);
#pragma unroll
        for (int i = 0; i < 4; i++) fr[row][c4 + i] = o4[i] / dn;
    }
    __syncthreads();

    int c = tid & 127, g = tid >> 7;
    int c2 = tid & 31, r = tid >> 5;

    // ---- phase 3a: policy hidden ----
    {
        float acc[4];
        float bb = bp1[c];
#pragma unroll
        for (int q = 0; q < 4; q++) acc[q] = bb;
#pragma unroll 8
        for (int k = 0; k < HID; k++) {
            float w = Wp1[k * HID + c];
#pragma unroll
            for (int q = 0; q < 4; q++) acc[q] += w * fr[g * 4 + q][k];
        }
#pragma unroll
        for (int q = 0; q < 4; q++) hh[g * 4 + q][c] = fmaxf(acc[q], 0.f);
    }
    __syncthreads();
    {   // policy out + softmax
        float lacc = bp2[c2];
#pragma unroll 8
        for (int k = 0; k < HID; k++) lacc += hh[r][k] * Wp2[k * 32 + c2];
        float mx = lacc;
#pragma unroll
        for (int s = 16; s >= 1; s >>= 1) mx = fmaxf(mx, __shfl_xor(mx, s, 32));
        float e = __expf(lacc - mx);
        float sm = e;
#pragma unroll
        for (int s = 16; s >= 1; s >>= 1) sm += __shfl_xor(sm, s, 32);
        out[(size_t)(r0 + r) * 32 + c2] = e / sm;
    }
    __syncthreads();

    // ---- phase 3b: value hidden (reuse hh) ----
    {
        float acc[4];
        float bb = bv1[c];
#pragma unroll
        for (int q = 0; q < 4; q++) acc[q] = bb;
#pragma unroll 8
        for (int k = 0; k < HID; k++) {
            float w = Wv1[k * HID + c];
#pragma unroll
            for (int q = 0; q < 4; q++) acc[q] += w * fr[g * 4 + q][k];
        }
#pragma unroll
        for (int q = 0; q < 4; q++) hh[g * 4 + q][c] = fmaxf(acc[q], 0.f);
    }
    __syncthreads();
    {   // value out
        float p = 0.f;
#pragma unroll
        for (int j = 0; j < 4; j++) p += hh[r][c2 + j * 32] * Wv2[c2 + j * 32];
#pragma unroll
        for (int s = 16; s >= 1; s >>= 1) p += __shfl_xor(p, s, 32);
        if (c2 == 0) out[131072 + r0 + r] = p + bv2[0];
    }
}

extern "C" void kernel_launch(void* const* d_in, const int* in_sizes, int n_in,
                              void* d_out, int out_size, void* d_ws, size_t ws_size,
                              hipStream_t stream) {
    const float* state = (const float*)d_in[0];
    const int*   adj   = (const int*)d_in[1];
    const float* W1  = (const float*)d_in[2];
    const float* b1  = (const float*)d_in[3];
    const float* W2  = (const float*)d_in[4];
    const float* b2  = (const float*)d_in[5];
    const float* Wg  = (const float*)d_in[6];
    const float* ag  = (const float*)d_in[7];
    const float* Wp1 = (const float*)d_in[8];
    const float* bp1 = (const float*)d_in[9];
    const float* Wp2 = (const float*)d_in[10];
    const float* bp2 = (const float*)d_in[11];
    const float* Wv1 = (const float*)d_in[12];
    const float* bv1 = (const float*)d_in[13];
    const float* Wv2 = (const float*)d_in[14];
    const float* bv2 = (const float*)d_in[15];
    float* out = (float*)d_out;
    float* ws = (float*)d_ws;

    unsigned short* hTf = (unsigned short*)ws;            // 524288 fp16
    float* s1b  = ws + 262144;
    float* s2b  = ws + 278528;
    unsigned short* E2h  = (unsigned short*)(ws + 294912);
    unsigned short* E2sh = (unsigned short*)(ws + 303104);
    float* cpos = ws + 311296;
    float* cneg = ws + 327680;
    unsigned int* abit = (unsigned int*)(ws + 344064);    // 2 MB
    __half* pout = (__half*)(ws + 868352);                // 4.2M fp16
    float* pden = ws + 2965504;

    hipLaunchKernelGGL(k_prep_pack, dim3(512 + NN), dim3(256), 0, stream,
                       state, W1, b1, W2, b2, Wg, ag, adj, hTf, s1b, s2b, abit);
    hipLaunchKernelGGL(k_headprep, dim3(HEADS), dim3(1024), 0, stream,
                       s1b, s2b, E2h, E2sh, cpos, cneg);
    hipLaunchKernelGGL(k_attn, dim3(32 * NSPLIT * HEADS), dim3(256), 0, stream,
                       abit, hTf, E2h, E2sh, cpos, cneg, pout, pden);
    hipLaunchKernelGGL(k_redpolval, dim3(NN / 16), dim3(512), 0, stream,
                       pout, pden, Wp1, bp1, Wp2, bp2, Wv1, bv1, Wv2, bv2, out);
}

// Round 13
// 62.367 us; speedup vs baseline: 1.3725x; 1.0485x over previous
//
#include <hip/hip_runtime.h>
#include <hip/hip_bf16.h>
#include <hip/hip_fp16.h>

#define NN 4096
#define SDIM 64
#define HID 128
#define HEADS 4
#define FF 32
#define NSPLIT 8

typedef __attribute__((ext_vector_type(8))) _Float16 h8;      // MFMA f16 A/B frag
typedef __attribute__((ext_vector_type(2))) _Float16 h2;
typedef __attribute__((ext_vector_type(4))) float f32x4;      // MFMA C/D
typedef __attribute__((ext_vector_type(4))) unsigned short us4;

__device__ inline h2 h2max(h2 a, h2 b) {
    h2 r; r[0] = a[0] > b[0] ? a[0] : b[0]; r[1] = a[1] > b[1] ? a[1] : b[1]; return r;
}

// ---------------- workspace layout (float units) ----------------
// hTf  : 0        (262144 f = 524288 fp16)  fragment-ordered h^T
// s1   : 262144   s2: 278528   (16384 each)
// abit : 294912   (524288 f = 2 MB bits)
// pout : 819200   (2097152 f = 4.2M fp16)   8 splits
// pden : 2916352  (131072)
// total 3047424 floats = 12.2 MB

// ============ K1: grid-partitioned prep (blocks 0..511, 8 rows each, LDS-staged W)
//                  + adjacency bit-pack (blocks 512..4607, 1 row each) ============
__global__ __launch_bounds__(256) void k_prep_pack(
        const float* __restrict__ state,
        const float* __restrict__ W1, const float* __restrict__ b1,
        const float* __restrict__ W2, const float* __restrict__ b2,
        const float* __restrict__ Wg, const float* __restrict__ ag,
        const int* __restrict__ adj,
        unsigned short* __restrict__ hTf,
        float* __restrict__ s1b, float* __restrict__ s2b,
        unsigned int* __restrict__ abit) {
    int tid = threadIdx.x;

    if (blockIdx.x >= 512) {
        // ---- pack branch: thread t packs 16 ints -> ushort ----
        int r = blockIdx.x - 512;
        const int4* ap = (const int4*)(adj + (size_t)r * NN + tid * 16);
        unsigned int b = 0;
#pragma unroll
        for (int i = 0; i < 4; i++) {
            int4 a = ap[i];
            b |= (unsigned int)(a.x != 0) << (i * 4 + 0);
            b |= (unsigned int)(a.y != 0) << (i * 4 + 1);
            b |= (unsigned int)(a.z != 0) << (i * 4 + 2);
            b |= (unsigned int)(a.w != 0) << (i * 4 + 3);
        }
        ((unsigned short*)abit)[r * 256 + tid] = (unsigned short)b;
        return;
    }

    // ---- prep branch: 8 rows/block, 256 threads, weights staged in LDS ----
    __shared__ float wbuf[8192];      // 32 KB staging (W1 | W2-half | Wg-half)
    __shared__ float srow[8][64];
    __shared__ float x1s[8][128];
    __shared__ float x2s[8][128];
    int r0 = blockIdx.x * 8;
    int c = tid & 127, g = tid >> 7;          // g = row-quad 0..1

    // stage state rows + W1 (8192 floats, coalesced float4)
    if (tid < 128)
        ((float4*)&srow[0][0])[tid] = ((const float4*)(state + (size_t)r0 * SDIM))[tid];
#pragma unroll
    for (int i = 0; i < 8; i++)
        ((float4*)wbuf)[tid + i * 256] = ((const float4*)W1)[tid + i * 256];
    __syncthreads();

    float acc[4];
    {   // x1 = relu(state@W1+b1), W1 from LDS
        float bb = b1[c];
#pragma unroll
        for (int r = 0; r < 4; r++) acc[r] = bb;
#pragma unroll 8
        for (int k = 0; k < SDIM; k++) {
            float w = wbuf[k * HID + c];
#pragma unroll
            for (int r = 0; r < 4; r++) acc[r] += w * srow[g * 4 + r][k];
        }
#pragma unroll
        for (int r = 0; r < 4; r++) x1s[g * 4 + r][c] = fmaxf(acc[r], 0.f);
    }

    {   // x2 = relu(x1@W2+b2), W2 staged in two 32 KB halves
        float bb = b2[c];
#pragma unroll
        for (int r = 0; r < 4; r++) acc[r] = bb;
#pragma unroll
        for (int hh = 0; hh < 2; hh++) {
            __syncthreads();
#pragma unroll
            for (int i = 0; i < 8; i++)
                ((float4*)wbuf)[tid + i * 256] = ((const float4*)(W2 + hh * 8192))[tid + i * 256];
            __syncthreads();
#pragma unroll 8
            for (int k = 0; k < 64; k++) {
                float w = wbuf[k * HID + c];
#pragma unroll
                for (int r = 0; r < 4; r++) acc[r] += w * x1s[g * 4 + r][hh * 64 + k];
            }
        }
#pragma unroll
        for (int r = 0; r < 4; r++) x2s[g * 4 + r][c] = fmaxf(acc[r], 0.f);
    }

    int hd = c >> 5, f = c & 31;
    float hacc[4];
#pragma unroll
    for (int r = 0; r < 4; r++) hacc[r] = 0.f;
    {   // h = x2 @ Wg, Wg staged in two halves; LDS index k*128 + hd*32 + f
#pragma unroll
        for (int hh = 0; hh < 2; hh++) {
            __syncthreads();
#pragma unroll
            for (int i = 0; i < 32; i++) {
                int L = tid + i * 256;
                int kk = L >> 7, cc = L & 127;
                wbuf[L] = Wg[(cc >> 5) * (HID * FF) + (hh * 64 + kk) * FF + (cc & 31)];
            }
            __syncthreads();
#pragma unroll 8
            for (int k = 0; k < 64; k++) {
                float w = wbuf[k * HID + c];
#pragma unroll
                for (int r = 0; r < 4; r++) hacc[r] += w * x2s[g * 4 + r][hh * 64 + k];
            }
        }
    }

    // h^T frag order (fp16): idx(hd,f,m) =
    //   ((hd*128 + (m>>5))*2 + (f>>4))*512 + (f&15)*32 + ((m&31)>>3)*8 + (m&7)
    {
        int bn = f >> 4, fr = f & 15;
        int m31 = (r0 & 31) + g * 4;
        us4 pk;
#pragma unroll
        for (int r = 0; r < 4; r++) pk[r] = __half_as_ushort(__float2half(hacc[r]));
        *(us4*)(hTf + (size_t)((hd * 128 + (r0 >> 5)) * 2 + bn) * 512
                + fr * 32 + (m31 >> 3) * 8 + (m31 & 7)) = pk;
    }

    float a1v = ag[hd * 64 + f];
    float a2v = ag[hd * 64 + 32 + f];
#pragma unroll
    for (int r = 0; r < 4; r++) {
        float p1 = hacc[r] * a1v;
        float p2 = hacc[r] * a2v;
#pragma unroll
        for (int s = 16; s >= 1; s >>= 1) {
            p1 += __shfl_xor(p1, s, 32);
            p2 += __shfl_xor(p2, s, 32);
        }
        if (f == 0) {
            s1b[hd * NN + r0 + g * 4 + r] = p1;
            s2b[hd * NN + r0 + g * 4 + r] = p2;
        }
    }
}

// ============ K2: attention — inline headprep, head-major, LDS-resident loop ============
// block: one head x 128 rows x 512 m; 256 thr = 4 waves (wave = 32-row band)
// grid: 32 row-tiles * 8 splits * 4 heads = 1024 blocks (LDS ~43.5KB -> 3/CU)
__global__ __launch_bounds__(256, 4) void k_attn(
        const unsigned int* __restrict__ abit, const unsigned short* __restrict__ hTf,
        const float* __restrict__ s1b, const float* __restrict__ s2b,
        __half* __restrict__ pout, float* __restrict__ pden) {
    __shared__ unsigned short hTl[16384];     // 32 KB, [ks*2+bn][lane] lane-linear frags
    __shared__ unsigned int abits[128][17];   // 128 rows x 16 words, padded
    __shared__ unsigned short e2l[512];       // fp16 E2 for this head's m-chunk
    __shared__ unsigned short esl[512];       // fp16 E2s
    __shared__ float redm[4];                 // per-wave s2 maxes

    int tid = threadIdx.x;
    int tile = blockIdx.x & 31;
    int split = (blockIdx.x >> 5) & 7;
    int hd = blockIdx.x >> 8;
    int nb = tile * 128, m0 = split * 512;

    {   // stage hT tile: 2048 frags (uint4), permuted src -> lane-linear LDS
#pragma unroll
        for (int i = 0; i < 8; i++) {
            int li = tid + i * 256;                     // (fb*2+bn)*64 + lane
            int lane2 = li & 63;
            int fr2 = lane2 & 15, mo2 = lane2 >> 4;
            int ksbn = li >> 6;                          // fb*2+bn
            const unsigned short* src = hTf
                + (size_t)((hd * 128 + (m0 >> 5) + (ksbn >> 1)) * 2 + (ksbn & 1)) * 512
                + fr2 * 32 + mo2 * 8;
            *(uint4*)&hTl[li * 8] = *(const uint4*)src;
        }
    }
    {   // stage adjacency: 128 rows x 16 words (2 uint4 per thread)
        int r = tid >> 1, q = (tid & 1) * 8;
        const unsigned int* src = abit + (size_t)(nb + r) * 128 + split * 16 + q;
        *(uint4*)&abits[r][q] = *(const uint4*)src;
        *(uint4*)&abits[r][q + 4] = *(const uint4*)(src + 4);
    }

    // inline headprep part 1: A2 = max over this head's full s2 row
    {
        float m = -1e30f;
        const f32x4* s2p4 = (const f32x4*)(s2b + hd * NN);
#pragma unroll
        for (int i = 0; i < 4; i++) {
            f32x4 v = s2p4[tid + i * 256];
            m = fmaxf(fmaxf(m, fmaxf(v[0], v[1])), fmaxf(v[2], v[3]));
        }
#pragma unroll
        for (int s = 32; s >= 1; s >>= 1) m = fmaxf(m, __shfl_xor(m, s, 64));
        if ((tid & 63) == 0) redm[tid >> 6] = m;
    }
    __syncthreads();
    float A2 = fmaxf(fmaxf(redm[0], redm[1]), fmaxf(redm[2], redm[3]));

    // inline headprep part 2: E2/E2s slices for this m-chunk (fp16, LDS)
#pragma unroll
    for (int i = 0; i < 2; i++) {
        int mm = tid + i * 256;
        float v2 = s2b[hd * NN + m0 + mm];
        e2l[mm] = __half_as_ushort(__float2half(__expf(v2 - A2)));
        esl[mm] = __half_as_ushort(__float2half(__expf(0.2f * (v2 - A2))));
    }

    int w = tid >> 6, lane = tid & 63;
    int fr = lane & 15, mo = lane >> 4;
    int nw0 = nb + w * 32;

    // inline headprep part 3: per-row cp/cn in registers
    h2 cph[2], cnh[2];
#pragma unroll
    for (int am = 0; am < 2; am++) {
        int n = nw0 + am * 16 + fr;
        float v1 = s1b[hd * NN + n];
        float u = v1 + A2;
        float C = fmaxf(u, 0.2f * u);
        _Float16 t1 = (_Float16)__expf(u - C);
        _Float16 t2 = (_Float16)__expf(0.2f * u - C);
        cph[am][0] = t1; cph[am][1] = t1;
        cnh[am][0] = t2; cnh[am][1] = t2;
    }
    __syncthreads();

    f32x4 acc[2][2];
    f32x4 accden[2];
#pragma unroll
    for (int am = 0; am < 2; am++) {
#pragma unroll
        for (int bn = 0; bn < 2; bn++) acc[am][bn] = (f32x4){0.f, 0.f, 0.f, 0.f};
        accden[am] = (f32x4){0.f, 0.f, 0.f, 0.f};
    }

    h8 ones;
#pragma unroll
    for (int j = 0; j < 8; j++) ones[j] = (_Float16)1.0f;

#pragma unroll 2
    for (int ks = 0; ks < 16; ks++) {
        h8 B0 = *(const h8*)&hTl[(ks * 2 + 0) * 512 + lane * 8];
        h8 B1 = *(const h8*)&hTl[(ks * 2 + 1) * 512 + lane * 8];
        uint4 e2v = *(const uint4*)&e2l[ks * 32 + mo * 8];
        uint4 esv = *(const uint4*)&esl[ks * 32 + mo * 8];

#pragma unroll
        for (int am = 0; am < 2; am++) {
            unsigned int bits = abits[w * 32 + am * 16 + fr][ks] >> (mo * 8);
            union { unsigned int u[4]; h8 v; } A;
#pragma unroll
            for (int p = 0; p < 4; p++) {
                unsigned int eu = (&e2v.x)[p], su = (&esv.x)[p];
                h2 e2h, esh;
                __builtin_memcpy(&e2h, &eu, 4);
                __builtin_memcpy(&esh, &su, 4);
                h2 w2 = h2max(cph[am] * e2h, cnh[am] * esh);
                unsigned int wm;
                __builtin_memcpy(&wm, &w2, 4);
                unsigned int b0 = (bits >> (2 * p)) & 1u;
                unsigned int b1 = (bits >> (2 * p + 1)) & 1u;
                wm &= ((0u - b0) & 0xFFFFu) | ((0u - b1) << 16);
                A.u[p] = wm;
            }
            acc[am][0] = __builtin_amdgcn_mfma_f32_16x16x32_f16(A.v, B0, acc[am][0], 0, 0, 0);
            acc[am][1] = __builtin_amdgcn_mfma_f32_16x16x32_f16(A.v, B1, acc[am][1], 0, 0, 0);
            accden[am] = __builtin_amdgcn_mfma_f32_16x16x32_f16(A.v, ones, accden[am], 0, 0, 0);
        }
    }

    __half* pob = pout + ((size_t)(split * 4 + hd) * NN + nw0) * FF;
#pragma unroll
    for (int am = 0; am < 2; am++) {
#pragma unroll
        for (int bn = 0; bn < 2; bn++) {
            f32x4 cv = acc[am][bn];
#pragma unroll
            for (int r = 0; r < 4; r++)
                pob[(am * 16 + mo * 4 + r) * FF + bn * 16 + fr] = __float2half(cv[r]);
        }
        // accden D-layout: row = mo*4+r, col = fr (all cols equal rowsum)
        if (fr == 0) {
#pragma unroll
            for (int r = 0; r < 4; r++)
                pden[(size_t)(split * 4 + hd) * NN + nw0 + am * 16 + mo * 4 + r] = accden[am][r];
        }
    }
}

// ============ K3: fused reduce + policy + value (256 blocks x 512 thr) ============
__global__ __launch_bounds__(512) void k_redpolval(
        const __half* __restrict__ pout, const float* __restrict__ pden,
        const float* __restrict__ Wp1, const float* __restrict__ bp1,
        const float* __restrict__ Wp2, const float* __restrict__ bp2,
        const float* __restrict__ Wv1, const float* __restrict__ bv1,
        const float* __restrict__ Wv2, const float* __restrict__ bv2,
        float* __restrict__ out) {
    __shared__ float fr[16][128];
    __shared__ float hh[16][128];
    __shared__ float dens[16][4];
    int tid = threadIdx.x;
    int r0 = blockIdx.x * 16;

    // ---- phase 1: den[n][hd] = sum over 8 splits ----
    {
        int p = tid >> 3, sg = tid & 7;     // p = r*4+hd
        int r = p >> 2, hd = p & 3;
        float d = pden[(size_t)(sg * 4 + hd) * NN + r0 + r];
#pragma unroll
        for (int s = 4; s >= 1; s >>= 1) d += __shfl_xor(d, s, 8);
        if (sg == 0) dens[r][hd] = d;
    }

    // ---- phase 2: feat = (sum of fp16 partials) / den ----
    int row = tid >> 5, c4 = (tid & 31) * 4;
    int hd2 = c4 >> 5;
    float o4[4] = {0.f, 0.f, 0.f, 0.f};
    const __half* pp = pout + ((size_t)hd2 * NN + r0 + row) * 32 + (c4 & 31);
#pragma unroll
    for (int s = 0; s < NSPLIT; s++) {
        float2 raw = *(const float2*)(pp + (size_t)s * 4 * NN * 32);
        __half2 ha = *(__half2*)&raw.x;
        __half2 hb = *(__half2*)&raw.y;
        float2 fa = __half22float2(ha), fb = __half22float2(hb);
        o4[0] += fa.x; o4[1] += fa.y; o4[2] += fb.x; o4[3] += fb.y;
    }
    __syncthreads();
    {
        float dn = fmaxf(dens[row][hd2], 1e-30f);
#pragma unroll
        for (int i = 0; i < 4; i++) fr[row][c4 + i] = o4[i] / dn;
    }
    __syncthreads();

    int c = tid & 127, g = tid >> 7;
    int c2 = tid & 31, r = tid >> 5;

    // ---- phase 3a: policy hidden ----
    {
        float acc[4];
        float bb = bp1[c];
#pragma unroll
        for (int q = 0; q < 4; q++) acc[q] = bb;
#pragma unroll 8
        for (int k = 0; k < HID; k++) {
            float w = Wp1[k * HID + c];
#pragma unroll
            for (int q = 0; q < 4; q++) acc[q] += w * fr[g * 4 + q][k];
        }
#pragma unroll
        for (int q = 0; q < 4; q++) hh[g * 4 + q][c] = fmaxf(acc[q], 0.f);
    }
    __syncthreads();
    {   // policy out + softmax
        float lacc = bp2[c2];
#pragma unroll 8
        for (int k = 0; k < HID; k++) lacc += hh[r][k] * Wp2[k * 32 + c2];
        float mx = lacc;
#pragma unroll
        for (int s = 16; s >= 1; s >>= 1) mx = fmaxf(mx, __shfl_xor(mx, s, 32));
        float e = __expf(lacc - mx);
        float sm = e;
#pragma unroll
        for (int s = 16; s >= 1; s >>= 1) sm += __shfl_xor(sm, s, 32);
        out[(size_t)(r0 + r) * 32 + c2] = e / sm;
    }
    __syncthreads();

    // ---- phase 3b: value hidden (reuse hh) ----
    {
        float acc[4];
        float bb = bv1[c];
#pragma unroll
        for (int q = 0; q < 4; q++) acc[q] = bb;
#pragma unroll 8
        for (int k = 0; k < HID; k++) {
            float w = Wv1[k * HID + c];
#pragma unroll
            for (int q = 0; q < 4; q++) acc[q] += w * fr[g * 4 + q][k];
        }
#pragma unroll
        for (int q = 0; q < 4; q++) hh[g * 4 + q][c] = fmaxf(acc[q], 0.f);
    }
    __syncthreads();
    {   // value out
        float p = 0.f;
#pragma unroll
        for (int j = 0; j < 4; j++) p += hh[r][c2 + j * 32] * Wv2[c2 + j * 32];
#pragma unroll
        for (int s = 16; s >= 1; s >>= 1) p += __shfl_xor(p, s, 32);
        if (c2 == 0) out[131072 + r0 + r] = p + bv2[0];
    }
}

extern "C" void kernel_launch(void* const* d_in, const int* in_sizes, int n_in,
                              void* d_out, int out_size, void* d_ws, size_t ws_size,
                              hipStream_t stream) {
    const float* state = (const float*)d_in[0];
    const int*   adj   = (const int*)d_in[1];
    const float* W1  = (const float*)d_in[2];
    const float* b1  = (const float*)d_in[3];
    const float* W2  = (const float*)d_in[4];
    const float* b2  = (const float*)d_in[5];
    const float* Wg  = (const float*)d_in[6];
    const float* ag  = (const float*)d_in[7];
    const float* Wp1 = (const float*)d_in[8];
    const float* bp1 = (const float*)d_in[9];
    const float* Wp2 = (const float*)d_in[10];
    const float* bp2 = (const float*)d_in[11];
    const float* Wv1 = (const float*)d_in[12];
    const float* bv1 = (const float*)d_in[13];
    const float* Wv2 = (const float*)d_in[14];
    const float* bv2 = (const float*)d_in[15];
    float* out = (float*)d_out;
    float* ws = (float*)d_ws;

    unsigned short* hTf = (unsigned short*)ws;            // 524288 fp16
    float* s1b  = ws + 262144;
    float* s2b  = ws + 278528;
    unsigned int* abit = (unsigned int*)(ws + 294912);    // 2 MB
    __half* pout = (__half*)(ws + 819200);                // 4.2M fp16
    float* pden = ws + 2916352;

    hipLaunchKernelGGL(k_prep_pack, dim3(512 + NN), dim3(256), 0, stream,
                       state, W1, b1, W2, b2, Wg, ag, adj, hTf, s1b, s2b, abit);
    hipLaunchKernelGGL(k_attn, dim3(32 * NSPLIT * HEADS), dim3(256), 0, stream,
                       abit, hTf, s1b, s2b, pout, pden);
    hipLaunchKernelGGL(k_redpolval, dim3(NN / 16), dim3(512), 0, stream,
                       pout, pden, Wp1, bp1, Wp2, bp2, Wv1, bv1, Wv2, bv2, out);
}

// Round 15
// 55.134 us; speedup vs baseline: 1.5526x; 1.1312x over previous
//
#include <hip/hip_runtime.h>
#include <hip/hip_bf16.h>
#include <hip/hip_fp16.h>

#define NN 4096
#define SDIM 64
#define HID 128
#define HEADS 4
#define FF 32
#define NSPLIT 8

typedef __attribute__((ext_vector_type(8))) _Float16 h8;      // MFMA f16 A/B frag
typedef __attribute__((ext_vector_type(2))) _Float16 h2;      // packed half2
typedef __attribute__((ext_vector_type(4))) float f32x4;      // MFMA C/D
typedef __attribute__((ext_vector_type(4))) unsigned short us4;

// ---------------- workspace layout (float units) ----------------
// hTf  : 0        (262144 f = 524288 fp16)  fragment-ordered h^T
// s1   : 262144   s2: 278528   (16384 each)
// abit : 294912   (524288 f = 2 MB bits)
// pout : 819200   (2097152 f = 4.2M fp16)   8 splits
// pden : 2916352  (131072)
// total 3047424 floats = 12.2 MB

// ============ K1: grid-partitioned prep (blocks 0..511, 8 rows each, LDS-staged W)
//                  + adjacency bit-pack (blocks 512..4607, 1 row each) ============
__global__ __launch_bounds__(256) void k_prep_pack(
        const float* __restrict__ state,
        const float* __restrict__ W1, const float* __restrict__ b1,
        const float* __restrict__ W2, const float* __restrict__ b2,
        const float* __restrict__ Wg, const float* __restrict__ ag,
        const int* __restrict__ adj,
        unsigned short* __restrict__ hTf,
        float* __restrict__ s1b, float* __restrict__ s2b,
        unsigned int* __restrict__ abit) {
    int tid = threadIdx.x;

    if (blockIdx.x >= 512) {
        // ---- pack branch: thread t packs 16 ints -> ushort ----
        int r = blockIdx.x - 512;
        const int4* ap = (const int4*)(adj + (size_t)r * NN + tid * 16);
        unsigned int b = 0;
#pragma unroll
        for (int i = 0; i < 4; i++) {
            int4 a = ap[i];
            b |= (unsigned int)(a.x != 0) << (i * 4 + 0);
            b |= (unsigned int)(a.y != 0) << (i * 4 + 1);
            b |= (unsigned int)(a.z != 0) << (i * 4 + 2);
            b |= (unsigned int)(a.w != 0) << (i * 4 + 3);
        }
        ((unsigned short*)abit)[r * 256 + tid] = (unsigned short)b;
        return;
    }

    // ---- prep branch: 8 rows/block, 256 threads, weights staged in LDS ----
    __shared__ float wbuf[8192];      // 32 KB staging (W1 | W2-half | Wg-half)
    __shared__ float srow[8][64];
    __shared__ float x1s[8][128];
    __shared__ float x2s[8][128];
    int r0 = blockIdx.x * 8;
    int c = tid & 127, g = tid >> 7;          // g = row-quad 0..1

    // stage state rows + W1 (8192 floats, coalesced float4)
    if (tid < 128)
        ((float4*)&srow[0][0])[tid] = ((const float4*)(state + (size_t)r0 * SDIM))[tid];
#pragma unroll
    for (int i = 0; i < 8; i++)
        ((float4*)wbuf)[tid + i * 256] = ((const float4*)W1)[tid + i * 256];
    __syncthreads();

    float acc[4];
    {   // x1 = relu(state@W1+b1), W1 from LDS
        float bb = b1[c];
#pragma unroll
        for (int r = 0; r < 4; r++) acc[r] = bb;
#pragma unroll 8
        for (int k = 0; k < SDIM; k++) {
            float w = wbuf[k * HID + c];
#pragma unroll
            for (int r = 0; r < 4; r++) acc[r] += w * srow[g * 4 + r][k];
        }
#pragma unroll
        for (int r = 0; r < 4; r++) x1s[g * 4 + r][c] = fmaxf(acc[r], 0.f);
    }

    {   // x2 = relu(x1@W2+b2), W2 staged in two 32 KB halves
        float bb = b2[c];
#pragma unroll
        for (int r = 0; r < 4; r++) acc[r] = bb;
#pragma unroll
        for (int hh = 0; hh < 2; hh++) {
            __syncthreads();
#pragma unroll
            for (int i = 0; i < 8; i++)
                ((float4*)wbuf)[tid + i * 256] = ((const float4*)(W2 + hh * 8192))[tid + i * 256];
            __syncthreads();
#pragma unroll 8
            for (int k = 0; k < 64; k++) {
                float w = wbuf[k * HID + c];
#pragma unroll
                for (int r = 0; r < 4; r++) acc[r] += w * x1s[g * 4 + r][hh * 64 + k];
            }
        }
#pragma unroll
        for (int r = 0; r < 4; r++) x2s[g * 4 + r][c] = fmaxf(acc[r], 0.f);
    }

    int hd = c >> 5, f = c & 31;
    float hacc[4];
#pragma unroll
    for (int r = 0; r < 4; r++) hacc[r] = 0.f;
    {   // h = x2 @ Wg, Wg staged in two halves; LDS index k*128 + hd*32 + f
#pragma unroll
        for (int hh = 0; hh < 2; hh++) {
            __syncthreads();
#pragma unroll
            for (int i = 0; i < 32; i++) {
                int L = tid + i * 256;
                int kk = L >> 7, cc = L & 127;
                wbuf[L] = Wg[(cc >> 5) * (HID * FF) + (hh * 64 + kk) * FF + (cc & 31)];
            }
            __syncthreads();
#pragma unroll 8
            for (int k = 0; k < 64; k++) {
                float w = wbuf[k * HID + c];
#pragma unroll
                for (int r = 0; r < 4; r++) hacc[r] += w * x2s[g * 4 + r][hh * 64 + k];
            }
        }
    }

    // h^T frag order (fp16): idx(hd,f,m) =
    //   ((hd*128 + (m>>5))*2 + (f>>4))*512 + (f&15)*32 + ((m&31)>>3)*8 + (m&7)
    {
        int bn = f >> 4, fr = f & 15;
        int m31 = (r0 & 31) + g * 4;
        us4 pk;
#pragma unroll
        for (int r = 0; r < 4; r++) pk[r] = __half_as_ushort(__float2half(hacc[r]));
        *(us4*)(hTf + (size_t)((hd * 128 + (r0 >> 5)) * 2 + bn) * 512
                + fr * 32 + (m31 >> 3) * 8 + (m31 & 7)) = pk;
    }

    float a1v = ag[hd * 64 + f];
    float a2v = ag[hd * 64 + 32 + f];
#pragma unroll
    for (int r = 0; r < 4; r++) {
        float p1 = hacc[r] * a1v;
        float p2 = hacc[r] * a2v;
#pragma unroll
        for (int s = 16; s >= 1; s >>= 1) {
            p1 += __shfl_xor(p1, s, 32);
            p2 += __shfl_xor(p2, s, 32);
        }
        if (f == 0) {
            s1b[hd * NN + r0 + g * 4 + r] = p1;
            s2b[hd * NN + r0 + g * 4 + r] = p2;
        }
    }
}

// ============ K2: attention — inline headprep, packed-f16 w-build, mask LUT ============
// block: one head x 128 rows x 512 m; 256 thr = 4 waves (wave = 32-row band)
// grid: 32 row-tiles * 8 splits * 4 heads = 1024 blocks (LDS ~43.7KB -> 3/CU)
__global__ __launch_bounds__(256, 3) void k_attn(
        const unsigned int* __restrict__ abit, const unsigned short* __restrict__ hTf,
        const float* __restrict__ s1b, const float* __restrict__ s2b,
        __half* __restrict__ pout, float* __restrict__ pden) {
    __shared__ unsigned short hTl[16384];     // 32 KB, [ks*2+bn][lane] lane-linear frags
    __shared__ unsigned int abits[128][17];   // 128 rows x 16 words, padded
    __shared__ unsigned short e2l[512];       // fp16 E2 for this head's m-chunk
    __shared__ unsigned short esl[512];       // fp16 E2s
    __shared__ float redm[4];                 // per-wave s2 maxes
    __shared__ uint2 mlut[16];                // nibble -> two 32-bit half-pair masks

    int tid = threadIdx.x;
    int tile = blockIdx.x & 31;
    int split = (blockIdx.x >> 5) & 7;
    int hd = blockIdx.x >> 8;
    int nb = tile * 128, m0 = split * 512;

    if (tid < 16) {   // build mask LUT
        unsigned int lo = ((tid & 1) ? 0xFFFFu : 0u) | ((tid & 2) ? 0xFFFF0000u : 0u);
        unsigned int hi = ((tid & 4) ? 0xFFFFu : 0u) | ((tid & 8) ? 0xFFFF0000u : 0u);
        mlut[tid] = make_uint2(lo, hi);
    }
    {   // stage hT tile: 2048 frags (uint4), permuted src -> lane-linear LDS
#pragma unroll
        for (int i = 0; i < 8; i++) {
            int li = tid + i * 256;                     // (fb*2+bn)*64 + lane
            int lane2 = li & 63;
            int fr2 = lane2 & 15, mo2 = lane2 >> 4;
            int ksbn = li >> 6;                          // fb*2+bn
            const unsigned short* src = hTf
                + (size_t)((hd * 128 + (m0 >> 5) + (ksbn >> 1)) * 2 + (ksbn & 1)) * 512
                + fr2 * 32 + mo2 * 8;
            *(uint4*)&hTl[li * 8] = *(const uint4*)src;
        }
    }
    {   // stage adjacency: 128 rows x 16 words (2 uint4 per thread)
        int r = tid >> 1, q = (tid & 1) * 8;
        const unsigned int* src = abit + (size_t)(nb + r) * 128 + split * 16 + q;
        *(uint4*)&abits[r][q] = *(const uint4*)src;
        *(uint4*)&abits[r][q + 4] = *(const uint4*)(src + 4);
    }

    // inline headprep part 1: A2 = max over this head's full s2 row
    {
        float m = -1e30f;
        const f32x4* s2p4 = (const f32x4*)(s2b + hd * NN);
#pragma unroll
        for (int i = 0; i < 4; i++) {
            f32x4 v = s2p4[tid + i * 256];
            m = fmaxf(fmaxf(m, fmaxf(v[0], v[1])), fmaxf(v[2], v[3]));
        }
#pragma unroll
        for (int s = 32; s >= 1; s >>= 1) m = fmaxf(m, __shfl_xor(m, s, 64));
        if ((tid & 63) == 0) redm[tid >> 6] = m;
    }
    __syncthreads();
    float A2 = fmaxf(fmaxf(redm[0], redm[1]), fmaxf(redm[2], redm[3]));

    // inline headprep part 2: E2/E2s slices for this m-chunk (fp16, LDS)
#pragma unroll
    for (int i = 0; i < 2; i++) {
        int mm = tid + i * 256;
        float v2 = s2b[hd * NN + m0 + mm];
        e2l[mm] = __half_as_ushort(__float2half(__expf(v2 - A2)));
        esl[mm] = __half_as_ushort(__float2half(__expf(0.2f * (v2 - A2))));
    }

    int w = tid >> 6, lane = tid & 63;
    int fr = lane & 15, mo = lane >> 4;
    int nw0 = nb + w * 32;

    // inline headprep part 3: per-row cp/cn in registers (h2 broadcast)
    h2 cph[2], cnh[2];
#pragma unroll
    for (int am = 0; am < 2; am++) {
        int n = nw0 + am * 16 + fr;
        float v1 = s1b[hd * NN + n];
        float u = v1 + A2;
        float C = fmaxf(u, 0.2f * u);
        _Float16 t1 = (_Float16)__expf(u - C);
        _Float16 t2 = (_Float16)__expf(0.2f * u - C);
        cph[am][0] = t1; cph[am][1] = t1;
        cnh[am][0] = t2; cnh[am][1] = t2;
    }
    __syncthreads();

    f32x4 acc[2][2];
    f32x4 accden[2];
#pragma unroll
    for (int am = 0; am < 2; am++) {
#pragma unroll
        for (int bn = 0; bn < 2; bn++) acc[am][bn] = (f32x4){0.f, 0.f, 0.f, 0.f};
        accden[am] = (f32x4){0.f, 0.f, 0.f, 0.f};
    }

    h8 ones;
#pragma unroll
    for (int j = 0; j < 8; j++) ones[j] = (_Float16)1.0f;

#pragma unroll 2
    for (int ks = 0; ks < 16; ks++) {
        h8 B0 = *(const h8*)&hTl[(ks * 2 + 0) * 512 + lane * 8];
        h8 B1 = *(const h8*)&hTl[(ks * 2 + 1) * 512 + lane * 8];
        const h2* e2p = (const h2*)&e2l[ks * 32 + mo * 8];
        const h2* esp = (const h2*)&esl[ks * 32 + mo * 8];

#pragma unroll
        for (int am = 0; am < 2; am++) {
            unsigned int bits = abits[w * 32 + am * 16 + fr][ks] >> (mo * 8);
            uint2 m01 = mlut[bits & 15];
            uint2 m23 = mlut[(bits >> 4) & 15];
            union { unsigned int u[4]; h8 v; } A;
#pragma unroll
            for (int p = 0; p < 4; p++) {
                h2 w2 = __builtin_elementwise_max(cph[am] * e2p[p], cnh[am] * esp[p]);
                unsigned int wm;
                __builtin_memcpy(&wm, &w2, 4);
                unsigned int mk = (p == 0) ? m01.x : (p == 1) ? m01.y : (p == 2) ? m23.x : m23.y;
                A.u[p] = wm & mk;
            }
            acc[am][0] = __builtin_amdgcn_mfma_f32_16x16x32_f16(A.v, B0, acc[am][0], 0, 0, 0);
            acc[am][1] = __builtin_amdgcn_mfma_f32_16x16x32_f16(A.v, B1, acc[am][1], 0, 0, 0);
            accden[am] = __builtin_amdgcn_mfma_f32_16x16x32_f16(A.v, ones, accden[am], 0, 0, 0);
        }
    }

    __half* pob = pout + ((size_t)(split * 4 + hd) * NN + nw0) * FF;
#pragma unroll
    for (int am = 0; am < 2; am++) {
#pragma unroll
        for (int bn = 0; bn < 2; bn++) {
            f32x4 cv = acc[am][bn];
#pragma unroll
            for (int r = 0; r < 4; r++)
                pob[(am * 16 + mo * 4 + r) * FF + bn * 16 + fr] = __float2half(cv[r]);
        }
        // accden D-layout: row = mo*4+r, col = fr (all cols equal rowsum)
        if (fr == 0) {
#pragma unroll
            for (int r = 0; r < 4; r++)
                pden[(size_t)(split * 4 + hd) * NN + nw0 + am * 16 + mo * 4 + r] = accden[am][r];
        }
    }
}

// ============ K3: fused reduce + policy + value (256 blocks x 512 thr) ============
__global__ __launch_bounds__(512) void k_redpolval(
        const __half* __restrict__ pout, const float* __restrict__ pden,
        const float* __restrict__ Wp1, const float* __restrict__ bp1,
        const float* __restrict__ Wp2, const float* __restrict__ bp2,
        const float* __restrict__ Wv1, const float* __restrict__ bv1,
        const float* __restrict__ Wv2, const float* __restrict__ bv2,
        float* __restrict__ out) {
    __shared__ float fr[16][128];
    __shared__ float hh[16][128];
    __shared__ float dens[16][4];
    int tid = threadIdx.x;
    int r0 = blockIdx.x * 16;

    // ---- phase 1: den[n][hd] = sum over 8 splits ----
    {
        int p = tid >> 3, sg = tid & 7;     // p = r*4+hd
        int r = p >> 2, hd = p & 3;
        float d = pden[(size_t)(sg * 4 + hd) * NN + r0 + r];
#pragma unroll
        for (int s = 4; s >= 1; s >>= 1) d += __shfl_xor(d, s, 8);
        if (sg == 0) dens[r][hd] = d;
    }

    // ---- phase 2: feat = (sum of fp16 partials) / den ----
    int row = tid >> 5, c4 = (tid & 31) * 4;
    int hd2 = c4 >> 5;
    float o4[4] = {0.f, 0.f, 0.f, 0.f};
    const __half* pp = pout + ((size_t)hd2 * NN + r0 + row) * 32 + (c4 & 31);
#pragma unroll
    for (int s = 0; s < NSPLIT; s++) {
        float2 raw = *(const float2*)(pp + (size_t)s * 4 * NN * 32);
        __half2 ha = *(__half2*)&raw.x;
        __half2 hb = *(__half2*)&raw.y;
        float2 fa = __half22float2(ha), fb = __half22float2(hb);
        o4[0] += fa.x; o4[1] += fa.y; o4[2] += fb.x; o4[3] += fb.y;
    }
    __syncthreads();
    {
        float dn = fmaxf(dens[row][hd2], 1e-30f);
#pragma unroll
        for (int i = 0; i < 4; i++) fr[row][c4 + i] = o4[i] / dn;
    }
    __syncthreads();

    int c = tid & 127, g = tid >> 7;
    int c2 = tid & 31, r = tid >> 5;

    // ---- phase 3a: policy hidden ----
    {
        float acc[4];
        float bb = bp1[c];
#pragma unroll
        for (int q = 0; q < 4; q++) acc[q] = bb;
#pragma unroll 8
        for (int k = 0; k < HID; k++) {
            float w = Wp1[k * HID + c];
#pragma unroll
            for (int q = 0; q < 4; q++) acc[q] += w * fr[g * 4 + q][k];
        }
#pragma unroll
        for (int q = 0; q < 4; q++) hh[g * 4 + q][c] = fmaxf(acc[q], 0.f);
    }
    __syncthreads();
    {   // policy out + softmax
        float lacc = bp2[c2];
#pragma unroll 8
        for (int k = 0; k < HID; k++) lacc += hh[r][k] * Wp2[k * 32 + c2];
        float mx = lacc;
#pragma unroll
        for (int s = 16; s >= 1; s >>= 1) mx = fmaxf(mx, __shfl_xor(mx, s, 32));
        float e = __expf(lacc - mx);
        float sm = e;
#pragma unroll
        for (int s = 16; s >= 1; s >>= 1) sm += __shfl_xor(sm, s, 32);
        out[(size_t)(r0 + r) * 32 + c2] = e / sm;
    }
    __syncthreads();

    // ---- phase 3b: value hidden (reuse hh) ----
    {
        float acc[4];
        float bb = bv1[c];
#pragma unroll
        for (int q = 0; q < 4; q++) acc[q] = bb;
#pragma unroll 8
        for (int k = 0; k < HID; k++) {
            float w = Wv1[k * HID + c];
#pragma unroll
            for (int q = 0; q < 4; q++) acc[q] += w * fr[g * 4 + q][k];
        }
#pragma unroll
        for (int q = 0; q < 4; q++) hh[g * 4 + q][c] = fmaxf(acc[q], 0.f);
    }
    __syncthreads();
    {   // value out
        float p = 0.f;
#pragma unroll
        for (int j = 0; j < 4; j++) p += hh[r][c2 + j * 32] * Wv2[c2 + j * 32];
#pragma unroll
        for (int s = 16; s >= 1; s >>= 1) p += __shfl_xor(p, s, 32);
        if (c2 == 0) out[131072 + r0 + r] = p + bv2[0];
    }
}

extern "C" void kernel_launch(void* const* d_in, const int* in_sizes, int n_in,
                              void* d_out, int out_size, void* d_ws, size_t ws_size,
                              hipStream_t stream) {
    const float* state = (const float*)d_in[0];
    const int*   adj   = (const int*)d_in[1];
    const float* W1  = (const float*)d_in[2];
    const float* b1  = (const float*)d_in[3];
    const float* W2  = (const float*)d_in[4];
    const float* b2  = (const float*)d_in[5];
    const float* Wg  = (const float*)d_in[6];
    const float* ag  = (const float*)d_in[7];
    const float* Wp1 = (const float*)d_in[8];
    const float* bp1 = (const float*)d_in[9];
    const float* Wp2 = (const float*)d_in[10];
    const float* bp2 = (const float*)d_in[11];
    const float* Wv1 = (const float*)d_in[12];
    const float* bv1 = (const float*)d_in[13];
    const float* Wv2 = (const float*)d_in[14];
    const float* bv2 = (const float*)d_in[15];
    float* out = (float*)d_out;
    float* ws = (float*)d_ws;

    unsigned short* hTf = (unsigned short*)ws;            // 524288 fp16
    float* s1b  = ws + 262144;
    float* s2b  = ws + 278528;
    unsigned int* abit = (unsigned int*)(ws + 294912);    // 2 MB
    __half* pout = (__half*)(ws + 819200);                // 4.2M fp16
    float* pden = ws + 2916352;

    hipLaunchKernelGGL(k_prep_pack, dim3(512 + NN), dim3(256), 0, stream,
                       state, W1, b1, W2, b2, Wg, ag, adj, hTf, s1b, s2b, abit);
    hipLaunchKernelGGL(k_attn, dim3(32 * NSPLIT * HEADS), dim3(256), 0, stream,
                       abit, hTf, s1b, s2b, pout, pden);
    hipLaunchKernelGGL(k_redpolval, dim3(NN / 16), dim3(512), 0, stream,
                       pout, pden, Wp1, bp1, Wp2, bp2, Wv1, bv1, Wv2, bv2, out);
}

// Round 17
// 54.781 us; speedup vs baseline: 1.5625x; 1.0064x over previous
//
#include <hip/hip_runtime.h>
#include <hip/hip_cooperative_groups.h>
#include <hip/hip_fp16.h>

#define NN 4096
#define SDIM 64
#define HID 128
#define HEADS 4
#define FF 32
#define NSPLIT 16      // fused path
#define NSPLIT_FB 8    // fallback path

typedef __attribute__((ext_vector_type(8))) _Float16 h8;      // MFMA f16 A/B frag
typedef __attribute__((ext_vector_type(2))) _Float16 h2;      // packed half2
typedef __attribute__((ext_vector_type(4))) float f32x4;      // MFMA C/D
typedef __attribute__((ext_vector_type(4))) unsigned short us4;

// ---------------- workspace layout (float units) ----------------
// hTf  : 0        (262144 f = 524288 fp16)  fragment-ordered h^T
// s1   : 262144   s2: 278528   (16384 each)
// abit : 294912   (524288 f = 2 MB bits)
// pout : 819200   (4194304 f = 8.4M fp16 max, 16 splits; fallback uses first 8)
// pden : 5013504  (262144)
// total 5275648 floats = 21.1 MB

// ==================== FUSED cooperative kernel ====================
// grid 512 x 256, bounds (256,2) -> 2 blocks/CU co-residency guaranteed
__global__ __launch_bounds__(256, 2) void k_fused(
        const float* __restrict__ state,
        const float* __restrict__ W1, const float* __restrict__ b1,
        const float* __restrict__ W2, const float* __restrict__ b2,
        const float* __restrict__ Wg, const float* __restrict__ ag,
        const int* __restrict__ adj,
        const float* __restrict__ Wp1, const float* __restrict__ bp1,
        const float* __restrict__ Wp2, const float* __restrict__ bp2,
        const float* __restrict__ Wv1, const float* __restrict__ bv1,
        const float* __restrict__ Wv2, const float* __restrict__ bv2,
        unsigned short* __restrict__ hTf,
        float* __restrict__ s1b, float* __restrict__ s2b,
        unsigned int* __restrict__ abit,
        __half* __restrict__ pout, float* __restrict__ pden,
        float* __restrict__ out) {
    __shared__ __align__(16) unsigned char smem[26624];
    cooperative_groups::grid_group grid = cooperative_groups::this_grid();
    int tid = threadIdx.x;
    int bid = blockIdx.x;

    // ========== P1: pack (bid 256..511, 16 rows each) / prep (bid 0..255, 2x8 rows) ==========
    if (bid >= 256) {
        int rb = (bid - 256) * 16;
#pragma unroll
        for (int rr = 0; rr < 16; rr++) {
            const int4* ap = (const int4*)(adj + (size_t)(rb + rr) * NN + tid * 16);
            unsigned int b = 0;
#pragma unroll
            for (int i = 0; i < 4; i++) {
                int4 a = ap[i];
                b |= (unsigned int)(a.x != 0) << (i * 4 + 0);
                b |= (unsigned int)(a.y != 0) << (i * 4 + 1);
                b |= (unsigned int)(a.z != 0) << (i * 4 + 2);
                b |= (unsigned int)(a.w != 0) << (i * 4 + 3);
            }
            ((unsigned short*)abit)[(rb + rr) * 256 + tid] = (unsigned short)b;
        }
    } else {
        float* wbuf = (float*)smem;                             // 16 KB
        float (*srow)[64] = (float(*)[64])(smem + 16384);       // 2 KB
        float (*x1s)[128] = (float(*)[128])(smem + 18432);      // 4 KB
        float (*x2s)[128] = (float(*)[128])(smem + 22528);      // 4 KB
        int c = tid & 127, g = tid >> 7;

        for (int uu = 0; uu < 2; uu++) {
            int r0 = (bid * 2 + uu) * 8;
            if (tid < 128)
                ((float4*)&srow[0][0])[tid] = ((const float4*)(state + (size_t)r0 * SDIM))[tid];

            float acc[4];
            {   // x1 = relu(state@W1+b1), W1 staged 2 x 16KB
                float bb = b1[c];
#pragma unroll
                for (int r = 0; r < 4; r++) acc[r] = bb;
#pragma unroll
                for (int q = 0; q < 2; q++) {
                    __syncthreads();
#pragma unroll
                    for (int i = 0; i < 4; i++)
                        ((float4*)wbuf)[tid + i * 256] = ((const float4*)(W1 + q * 4096))[tid + i * 256];
                    __syncthreads();
#pragma unroll 8
                    for (int k = 0; k < 32; k++) {
                        float w = wbuf[k * HID + c];
#pragma unroll
                        for (int r = 0; r < 4; r++) acc[r] += w * srow[g * 4 + r][q * 32 + k];
                    }
                }
#pragma unroll
                for (int r = 0; r < 4; r++) x1s[g * 4 + r][c] = fmaxf(acc[r], 0.f);
            }
            {   // x2 = relu(x1@W2+b2), W2 staged 4 x 16KB
                float bb = b2[c];
#pragma unroll
                for (int r = 0; r < 4; r++) acc[r] = bb;
#pragma unroll
                for (int q = 0; q < 4; q++) {
                    __syncthreads();
#pragma unroll
                    for (int i = 0; i < 4; i++)
                        ((float4*)wbuf)[tid + i * 256] = ((const float4*)(W2 + q * 4096))[tid + i * 256];
                    __syncthreads();
#pragma unroll 8
                    for (int k = 0; k < 32; k++) {
                        float w = wbuf[k * HID + c];
#pragma unroll
                        for (int r = 0; r < 4; r++) acc[r] += w * x1s[g * 4 + r][q * 32 + k];
                    }
                }
#pragma unroll
                for (int r = 0; r < 4; r++) x2s[g * 4 + r][c] = fmaxf(acc[r], 0.f);
            }
            int hd = c >> 5, f = c & 31;
            float hacc[4];
#pragma unroll
            for (int r = 0; r < 4; r++) hacc[r] = 0.f;
            {   // h = x2 @ Wg, staged 4 x 16KB; LDS index k*128 + hd*32 + f
#pragma unroll
                for (int q = 0; q < 4; q++) {
                    __syncthreads();
#pragma unroll
                    for (int i = 0; i < 16; i++) {
                        int L = tid + i * 256;
                        int kk = L >> 7, cc = L & 127;
                        wbuf[L] = Wg[(cc >> 5) * (HID * FF) + (q * 32 + kk) * FF + (cc & 31)];
                    }
                    __syncthreads();
#pragma unroll 8
                    for (int k = 0; k < 32; k++) {
                        float w = wbuf[k * HID + c];
#pragma unroll
                        for (int r = 0; r < 4; r++) hacc[r] += w * x2s[g * 4 + r][q * 32 + k];
                    }
                }
            }
            // h^T frag order (fp16): idx(hd,f,m) =
            //   ((hd*128 + (m>>5))*2 + (f>>4))*512 + (f&15)*32 + ((m&31)>>3)*8 + (m&7)
            {
                int bn = f >> 4, fr = f & 15;
                int m31 = (r0 & 31) + g * 4;
                us4 pk;
#pragma unroll
                for (int r = 0; r < 4; r++) pk[r] = __half_as_ushort(__float2half(hacc[r]));
                *(us4*)(hTf + (size_t)((hd * 128 + (r0 >> 5)) * 2 + bn) * 512
                        + fr * 32 + (m31 >> 3) * 8 + (m31 & 7)) = pk;
            }
            float a1v = ag[hd * 64 + f];
            float a2v = ag[hd * 64 + 32 + f];
#pragma unroll
            for (int r = 0; r < 4; r++) {
                float p1 = hacc[r] * a1v;
                float p2 = hacc[r] * a2v;
#pragma unroll
                for (int s = 16; s >= 1; s >>= 1) {
                    p1 += __shfl_xor(p1, s, 32);
                    p2 += __shfl_xor(p2, s, 32);
                }
                if (f == 0) {
                    s1b[hd * NN + r0 + g * 4 + r] = p1;
                    s2b[hd * NN + r0 + g * 4 + r] = p2;
                }
            }
        }
    }
    __threadfence();
    grid.sync();

    // ========== P2: attention, 4 works per block (2048 works = 32 tiles x 16 splits x 4 hd) ==========
    {
        unsigned short* hTl = (unsigned short*)smem;                    // 16384 B
        unsigned int (*abits)[9] = (unsigned int(*)[9])(smem + 16384);  // 4608 B
        unsigned short* e2l = (unsigned short*)(smem + 20992);          // 512 B
        unsigned short* esl = (unsigned short*)(smem + 21504);          // 512 B
        float* redm = (float*)(smem + 22016);                           // 16 B
        uint2* mlut = (uint2*)(smem + 22032);                           // 128 B

#pragma unroll 1
        for (int t = 0; t < 4; t++) {
            __syncthreads();
            int work = bid + t * 512;
            int tile = work & 31;
            int split = (work >> 5) & 15;
            int hd = work >> 9;
            int nb = tile * 128, m0 = split * 256;

            if (tid < 16) {
                unsigned int lo = ((tid & 1) ? 0xFFFFu : 0u) | ((tid & 2) ? 0xFFFF0000u : 0u);
                unsigned int hi = ((tid & 4) ? 0xFFFFu : 0u) | ((tid & 8) ? 0xFFFF0000u : 0u);
                mlut[tid] = make_uint2(lo, hi);
            }
            {   // stage hT tile: 1024 frags (uint4), permuted src -> lane-linear LDS
#pragma unroll
                for (int i = 0; i < 4; i++) {
                    int li = tid + i * 256;
                    int lane2 = li & 63;
                    int fr2 = lane2 & 15, mo2 = lane2 >> 4;
                    int ksbn = li >> 6;
                    const unsigned short* src = hTf
                        + (size_t)((hd * 128 + (m0 >> 5) + (ksbn >> 1)) * 2 + (ksbn & 1)) * 512
                        + fr2 * 32 + mo2 * 8;
                    *(uint4*)&hTl[li * 8] = *(const uint4*)src;
                }
            }
            {   // stage adjacency: 128 rows x 8 words
                int r = tid >> 1, q = (tid & 1) * 4;
                const unsigned int* src = abit + (size_t)(nb + r) * 128 + split * 8 + q;
                *(uint4*)&abits[r][q] = *(const uint4*)src;
            }
            // A2 = max over this head's full s2 row
            {
                float m = -1e30f;
                const f32x4* s2p4 = (const f32x4*)(s2b + hd * NN);
#pragma unroll
                for (int i = 0; i < 4; i++) {
                    f32x4 v = s2p4[tid + i * 256];
                    m = fmaxf(fmaxf(m, fmaxf(v[0], v[1])), fmaxf(v[2], v[3]));
                }
#pragma unroll
                for (int s = 32; s >= 1; s >>= 1) m = fmaxf(m, __shfl_xor(m, s, 64));
                if ((tid & 63) == 0) redm[tid >> 6] = m;
            }
            __syncthreads();
            float A2 = fmaxf(fmaxf(redm[0], redm[1]), fmaxf(redm[2], redm[3]));

            {   // E2/E2s slice (256 m)
                float v2 = s2b[hd * NN + m0 + tid];
                e2l[tid] = __half_as_ushort(__float2half(__expf(v2 - A2)));
                esl[tid] = __half_as_ushort(__float2half(__expf(0.2f * (v2 - A2))));
            }

            int w = tid >> 6, lane = tid & 63;
            int fr = lane & 15, mo = lane >> 4;
            int nw0 = nb + w * 32;

            h2 cph[2], cnh[2];
#pragma unroll
            for (int am = 0; am < 2; am++) {
                int n = nw0 + am * 16 + fr;
                float v1 = s1b[hd * NN + n];
                float u = v1 + A2;
                float C = fmaxf(u, 0.2f * u);
                _Float16 t1 = (_Float16)__expf(u - C);
                _Float16 t2 = (_Float16)__expf(0.2f * u - C);
                cph[am][0] = t1; cph[am][1] = t1;
                cnh[am][0] = t2; cnh[am][1] = t2;
            }
            __syncthreads();

            f32x4 acc[2][2];
            f32x4 accden[2];
#pragma unroll
            for (int am = 0; am < 2; am++) {
#pragma unroll
                for (int bn = 0; bn < 2; bn++) acc[am][bn] = (f32x4){0.f, 0.f, 0.f, 0.f};
                accden[am] = (f32x4){0.f, 0.f, 0.f, 0.f};
            }
            h8 ones;
#pragma unroll
            for (int j = 0; j < 8; j++) ones[j] = (_Float16)1.0f;

#pragma unroll 2
            for (int ks = 0; ks < 8; ks++) {
                h8 B0 = *(const h8*)&hTl[(ks * 2 + 0) * 512 + lane * 8];
                h8 B1 = *(const h8*)&hTl[(ks * 2 + 1) * 512 + lane * 8];
                const h2* e2p = (const h2*)&e2l[ks * 32 + mo * 8];
                const h2* esp = (const h2*)&esl[ks * 32 + mo * 8];

#pragma unroll
                for (int am = 0; am < 2; am++) {
                    unsigned int bits = abits[w * 32 + am * 16 + fr][ks] >> (mo * 8);
                    uint2 m01 = mlut[bits & 15];
                    uint2 m23 = mlut[(bits >> 4) & 15];
                    union { unsigned int u[4]; h8 v; } A;
#pragma unroll
                    for (int p = 0; p < 4; p++) {
                        h2 w2 = __builtin_elementwise_max(cph[am] * e2p[p], cnh[am] * esp[p]);
                        unsigned int wm;
                        __builtin_memcpy(&wm, &w2, 4);
                        unsigned int mk = (p == 0) ? m01.x : (p == 1) ? m01.y : (p == 2) ? m23.x : m23.y;
                        A.u[p] = wm & mk;
                    }
                    acc[am][0] = __builtin_amdgcn_mfma_f32_16x16x32_f16(A.v, B0, acc[am][0], 0, 0, 0);
                    acc[am][1] = __builtin_amdgcn_mfma_f32_16x16x32_f16(A.v, B1, acc[am][1], 0, 0, 0);
                    accden[am] = __builtin_amdgcn_mfma_f32_16x16x32_f16(A.v, ones, accden[am], 0, 0, 0);
                }
            }

            __half* pob = pout + ((size_t)(split * 4 + hd) * NN + nw0) * FF;
#pragma unroll
            for (int am = 0; am < 2; am++) {
#pragma unroll
                for (int bn = 0; bn < 2; bn++) {
                    f32x4 cv = acc[am][bn];
#pragma unroll
                    for (int r = 0; r < 4; r++)
                        pob[(am * 16 + mo * 4 + r) * FF + bn * 16 + fr] = __float2half(cv[r]);
                }
                if (fr == 0) {
#pragma unroll
                    for (int r = 0; r < 4; r++)
                        pden[(size_t)(split * 4 + hd) * NN + nw0 + am * 16 + mo * 4 + r] = accden[am][r];
                }
            }
        }
    }
    __threadfence();
    grid.sync();

    // ========== P3: reduce + policy + value (all 512 blocks, 8 rows each) ==========
    {
        float (*fr8)[128] = (float(*)[128])smem;                 // 4 KB
        float (*hh)[128] = (float(*)[128])(smem + 4096);         // 4 KB
        float (*dens)[4] = (float(*)[4])(smem + 8192);           // 128 B
        int r0 = bid * 8;
        __syncthreads();

        {   // dens: 8 rows x 4 heads, 16 splits
            int p = tid >> 3, sg = tid & 7;
            int r = p >> 2, hd = p & 3;
            float d = 0.f;
#pragma unroll
            for (int i = 0; i < 2; i++)
                d += pden[(size_t)((sg + i * 8) * 4 + hd) * NN + r0 + r];
#pragma unroll
            for (int s = 4; s >= 1; s >>= 1) d += __shfl_xor(d, s, 8);
            if (sg == 0) dens[r][hd] = d;
        }

        int row = tid >> 5, c4 = (tid & 31) * 4;
        int hd2 = c4 >> 5;
        float o4[4] = {0.f, 0.f, 0.f, 0.f};
        const __half* pp = pout + ((size_t)hd2 * NN + r0 + row) * 32 + (c4 & 31);
#pragma unroll
        for (int s = 0; s < NSPLIT; s++) {
            float2 raw = *(const float2*)(pp + (size_t)s * 4 * NN * 32);
            __half2 ha = *(__half2*)&raw.x;
            __half2 hb = *(__half2*)&raw.y;
            float2 fa = __half22float2(ha), fb = __half22float2(hb);
            o4[0] += fa.x; o4[1] += fa.y; o4[2] += fb.x; o4[3] += fb.y;
        }
        __syncthreads();
        {
            float dn = fmaxf(dens[row][hd2], 1e-30f);
#pragma unroll
            for (int i = 0; i < 4; i++) fr8[row][c4 + i] = o4[i] / dn;
        }
        __syncthreads();

        int c = tid & 127, g = tid >> 7;
        int c2 = tid & 31, r = tid >> 5;

        {   // policy hidden
            float acc[4];
            float bb = bp1[c];
#pragma unroll
            for (int q = 0; q < 4; q++) acc[q] = bb;
#pragma unroll 8
            for (int k = 0; k < HID; k++) {
                float w = Wp1[k * HID + c];
#pragma unroll
                for (int q = 0; q < 4; q++) acc[q] += w * fr8[g * 4 + q][k];
            }
#pragma unroll
            for (int q = 0; q < 4; q++) hh[g * 4 + q][c] = fmaxf(acc[q], 0.f);
        }
        __syncthreads();
        {   // policy out + softmax
            float lacc = bp2[c2];
#pragma unroll 8
            for (int k = 0; k < HID; k++) lacc += hh[r][k] * Wp2[k * 32 + c2];
            float mx = lacc;
#pragma unroll
            for (int s = 16; s >= 1; s >>= 1) mx = fmaxf(mx, __shfl_xor(mx, s, 32));
            float e = __expf(lacc - mx);
            float sm = e;
#pragma unroll
            for (int s = 16; s >= 1; s >>= 1) sm += __shfl_xor(sm, s, 32);
            out[(size_t)(r0 + r) * 32 + c2] = e / sm;
        }
        __syncthreads();
        {   // value hidden (reuse hh)
            float acc[4];
            float bb = bv1[c];
#pragma unroll
            for (int q = 0; q < 4; q++) acc[q] = bb;
#pragma unroll 8
            for (int k = 0; k < HID; k++) {
                float w = Wv1[k * HID + c];
#pragma unroll
                for (int q = 0; q < 4; q++) acc[q] += w * fr8[g * 4 + q][k];
            }
#pragma unroll
            for (int q = 0; q < 4; q++) hh[g * 4 + q][c] = fmaxf(acc[q], 0.f);
        }
        __syncthreads();
        {   // value out
            float p = 0.f;
#pragma unroll
            for (int j = 0; j < 4; j++) p += hh[r][c2 + j * 32] * Wv2[c2 + j * 32];
#pragma unroll
            for (int s = 16; s >= 1; s >>= 1) p += __shfl_xor(p, s, 32);
            if (c2 == 0) out[131072 + r0 + r] = p + bv2[0];
        }
    }
}

// ==================== FALLBACK: R15 3-kernel path (proven 55 µs) ====================
__global__ __launch_bounds__(256) void k_prep_pack(
        const float* __restrict__ state,
        const float* __restrict__ W1, const float* __restrict__ b1,
        const float* __restrict__ W2, const float* __restrict__ b2,
        const float* __restrict__ Wg, const float* __restrict__ ag,
        const int* __restrict__ adj,
        unsigned short* __restrict__ hTf,
        float* __restrict__ s1b, float* __restrict__ s2b,
        unsigned int* __restrict__ abit) {
    int tid = threadIdx.x;

    if (blockIdx.x >= 512) {
        int r = blockIdx.x - 512;
        const int4* ap = (const int4*)(adj + (size_t)r * NN + tid * 16);
        unsigned int b = 0;
#pragma unroll
        for (int i = 0; i < 4; i++) {
            int4 a = ap[i];
            b |= (unsigned int)(a.x != 0) << (i * 4 + 0);
            b |= (unsigned int)(a.y != 0) << (i * 4 + 1);
            b |= (unsigned int)(a.z != 0) << (i * 4 + 2);
            b |= (unsigned int)(a.w != 0) << (i * 4 + 3);
        }
        ((unsigned short*)abit)[r * 256 + tid] = (unsigned short)b;
        return;
    }

    __shared__ float wbuf[8192];
    __shared__ float srow[8][64];
    __shared__ float x1s[8][128];
    __shared__ float x2s[8][128];
    int r0 = blockIdx.x * 8;
    int c = tid & 127, g = tid >> 7;

    if (tid < 128)
        ((float4*)&srow[0][0])[tid] = ((const float4*)(state + (size_t)r0 * SDIM))[tid];
#pragma unroll
    for (int i = 0; i < 8; i++)
        ((float4*)wbuf)[tid + i * 256] = ((const float4*)W1)[tid + i * 256];
    __syncthreads();

    float acc[4];
    {
        float bb = b1[c];
#pragma unroll
        for (int r = 0; r < 4; r++) acc[r] = bb;
#pragma unroll 8
        for (int k = 0; k < SDIM; k++) {
            float w = wbuf[k * HID + c];
#pragma unroll
            for (int r = 0; r < 4; r++) acc[r] += w * srow[g * 4 + r][k];
        }
#pragma unroll
        for (int r = 0; r < 4; r++) x1s[g * 4 + r][c] = fmaxf(acc[r], 0.f);
    }
    {
        float bb = b2[c];
#pragma unroll
        for (int r = 0; r < 4; r++) acc[r] = bb;
#pragma unroll
        for (int hh = 0; hh < 2; hh++) {
            __syncthreads();
#pragma unroll
            for (int i = 0; i < 8; i++)
                ((float4*)wbuf)[tid + i * 256] = ((const float4*)(W2 + hh * 8192))[tid + i * 256];
            __syncthreads();
#pragma unroll 8
            for (int k = 0; k < 64; k++) {
                float w = wbuf[k * HID + c];
#pragma unroll
                for (int r = 0; r < 4; r++) acc[r] += w * x1s[g * 4 + r][hh * 64 + k];
            }
        }
#pragma unroll
        for (int r = 0; r < 4; r++) x2s[g * 4 + r][c] = fmaxf(acc[r], 0.f);
    }
    int hd = c >> 5, f = c & 31;
    float hacc[4];
#pragma unroll
    for (int r = 0; r < 4; r++) hacc[r] = 0.f;
    {
#pragma unroll
        for (int hh = 0; hh < 2; hh++) {
            __syncthreads();
#pragma unroll
            for (int i = 0; i < 32; i++) {
                int L = tid + i * 256;
                int kk = L >> 7, cc = L & 127;
                wbuf[L] = Wg[(cc >> 5) * (HID * FF) + (hh * 64 + kk) * FF + (cc & 31)];
            }
            __syncthreads();
#pragma unroll 8
            for (int k = 0; k < 64; k++) {
                float w = wbuf[k * HID + c];
#pragma unroll
                for (int r = 0; r < 4; r++) hacc[r] += w * x2s[g * 4 + r][hh * 64 + k];
            }
        }
    }
    {
        int bn = f >> 4, fr = f & 15;
        int m31 = (r0 & 31) + g * 4;
        us4 pk;
#pragma unroll
        for (int r = 0; r < 4; r++) pk[r] = __half_as_ushort(__float2half(hacc[r]));
        *(us4*)(hTf + (size_t)((hd * 128 + (r0 >> 5)) * 2 + bn) * 512
                + fr * 32 + (m31 >> 3) * 8 + (m31 & 7)) = pk;
    }
    float a1v = ag[hd * 64 + f];
    float a2v = ag[hd * 64 + 32 + f];
#pragma unroll
    for (int r = 0; r < 4; r++) {
        float p1 = hacc[r] * a1v;
        float p2 = hacc[r] * a2v;
#pragma unroll
        for (int s = 16; s >= 1; s >>= 1) {
            p1 += __shfl_xor(p1, s, 32);
            p2 += __shfl_xor(p2, s, 32);
        }
        if (f == 0) {
            s1b[hd * NN + r0 + g * 4 + r] = p1;
            s2b[hd * NN + r0 + g * 4 + r] = p2;
        }
    }
}

__global__ __launch_bounds__(256, 3) void k_attn_fb(
        const unsigned int* __restrict__ abit, const unsigned short* __restrict__ hTf,
        const float* __restrict__ s1b, const float* __restrict__ s2b,
        __half* __restrict__ pout, float* __restrict__ pden) {
    __shared__ unsigned short hTl[16384];
    __shared__ unsigned int abits[128][17];
    __shared__ unsigned short e2l[512];
    __shared__ unsigned short esl[512];
    __shared__ float redm[4];
    __shared__ uint2 mlut[16];

    int tid = threadIdx.x;
    int tile = blockIdx.x & 31;
    int split = (blockIdx.x >> 5) & 7;
    int hd = blockIdx.x >> 8;
    int nb = tile * 128, m0 = split * 512;

    if (tid < 16) {
        unsigned int lo = ((tid & 1) ? 0xFFFFu : 0u) | ((tid & 2) ? 0xFFFF0000u : 0u);
        unsigned int hi = ((tid & 4) ? 0xFFFFu : 0u) | ((tid & 8) ? 0xFFFF0000u : 0u);
        mlut[tid] = make_uint2(lo, hi);
    }
    {
#pragma unroll
        for (int i = 0; i < 8; i++) {
            int li = tid + i * 256;
            int lane2 = li & 63;
            int fr2 = lane2 & 15, mo2 = lane2 >> 4;
            int ksbn = li >> 6;
            const unsigned short* src = hTf
                + (size_t)((hd * 128 + (m0 >> 5) + (ksbn >> 1)) * 2 + (ksbn & 1)) * 512
                + fr2 * 32 + mo2 * 8;
            *(uint4*)&hTl[li * 8] = *(const uint4*)src;
        }
    }
    {
        int r = tid >> 1, q = (tid & 1) * 8;
        const unsigned int* src = abit + (size_t)(nb + r) * 128 + split * 16 + q;
        *(uint4*)&abits[r][q] = *(const uint4*)src;
        *(uint4*)&abits[r][q + 4] = *(const uint4*)(src + 4);
    }
    {
        float m = -1e30f;
        const f32x4* s2p4 = (const f32x4*)(s2b + hd * NN);
#pragma unroll
        for (int i = 0; i < 4; i++) {
            f32x4 v = s2p4[tid + i * 256];
            m = fmaxf(fmaxf(m, fmaxf(v[0], v[1])), fmaxf(v[2], v[3]));
        }
#pragma unroll
        for (int s = 32; s >= 1; s >>= 1) m = fmaxf(m, __shfl_xor(m, s, 64));
        if ((tid & 63) == 0) redm[tid >> 6] = m;
    }
    __syncthreads();
    float A2 = fmaxf(fmaxf(redm[0], redm[1]), fmaxf(redm[2], redm[3]));

#pragma unroll
    for (int i = 0; i < 2; i++) {
        int mm = tid + i * 256;
        float v2 = s2b[hd * NN + m0 + mm];
        e2l[mm] = __half_as_ushort(__float2half(__expf(v2 - A2)));
        esl[mm] = __half_as_ushort(__float2half(__expf(0.2f * (v2 - A2))));
    }

    int w = tid >> 6, lane = tid & 63;
    int fr = lane & 15, mo = lane >> 4;
    int nw0 = nb + w * 32;

    h2 cph[2], cnh[2];
#pragma unroll
    for (int am = 0; am < 2; am++) {
        int n = nw0 + am * 16 + fr;
        float v1 = s1b[hd * NN + n];
        float u = v1 + A2;
        float C = fmaxf(u, 0.2f * u);
        _Float16 t1 = (_Float16)__expf(u - C);
        _Float16 t2 = (_Float16)__expf(0.2f * u - C);
        cph[am][0] = t1; cph[am][1] = t1;
        cnh[am][0] = t2; cnh[am][1] = t2;
    }
    __syncthreads();

    f32x4 acc[2][2];
    f32x4 accden[2];
#pragma unroll
    for (int am = 0; am < 2; am++) {
#pragma unroll
        for (int bn = 0; bn < 2; bn++) acc[am][bn] = (f32x4){0.f, 0.f, 0.f, 0.f};
        accden[am] = (f32x4){0.f, 0.f, 0.f, 0.f};
    }
    h8 ones;
#pragma unroll
    for (int j = 0; j < 8; j++) ones[j] = (_Float16)1.0f;

#pragma unroll 2
    for (int ks = 0; ks < 16; ks++) {
        h8 B0 = *(const h8*)&hTl[(ks * 2 + 0) * 512 + lane * 8];
        h8 B1 = *(const h8*)&hTl[(ks * 2 + 1) * 512 + lane * 8];
        const h2* e2p = (const h2*)&e2l[ks * 32 + mo * 8];
        const h2* esp = (const h2*)&esl[ks * 32 + mo * 8];

#pragma unroll
        for (int am = 0; am < 2; am++) {
            unsigned int bits = abits[w * 32 + am * 16 + fr][ks] >> (mo * 8);
            uint2 m01 = mlut[bits & 15];
            uint2 m23 = mlut[(bits >> 4) & 15];
            union { unsigned int u[4]; h8 v; } A;
#pragma unroll
            for (int p = 0; p < 4; p++) {
                h2 w2 = __builtin_elementwise_max(cph[am] * e2p[p], cnh[am] * esp[p]);
                unsigned int wm;
                __builtin_memcpy(&wm, &w2, 4);
                unsigned int mk = (p == 0) ? m01.x : (p == 1) ? m01.y : (p == 2) ? m23.x : m23.y;
                A.u[p] = wm & mk;
            }
            acc[am][0] = __builtin_amdgcn_mfma_f32_16x16x32_f16(A.v, B0, acc[am][0], 0, 0, 0);
            acc[am][1] = __builtin_amdgcn_mfma_f32_16x16x32_f16(A.v, B1, acc[am][1], 0, 0, 0);
            accden[am] = __builtin_amdgcn_mfma_f32_16x16x32_f16(A.v, ones, accden[am], 0, 0, 0);
        }
    }

    __half* pob = pout + ((size_t)(split * 4 + hd) * NN + nw0) * FF;
#pragma unroll
    for (int am = 0; am < 2; am++) {
#pragma unroll
        for (int bn = 0; bn < 2; bn++) {
            f32x4 cv = acc[am][bn];
#pragma unroll
            for (int r = 0; r < 4; r++)
                pob[(am * 16 + mo * 4 + r) * FF + bn * 16 + fr] = __float2half(cv[r]);
        }
        if (fr == 0) {
#pragma unroll
            for (int r = 0; r < 4; r++)
                pden[(size_t)(split * 4 + hd) * NN + nw0 + am * 16 + mo * 4 + r] = accden[am][r];
        }
    }
}

__global__ __launch_bounds__(512) void k_redpolval_fb(
        const __half* __restrict__ pout, const float* __restrict__ pden,
        const float* __restrict__ Wp1, const float* __restrict__ bp1,
        const float* __restrict__ Wp2, const float* __restrict__ bp2,
        const float* __restrict__ Wv1, const float* __restrict__ bv1,
        const float* __restrict__ Wv2, const float* __restrict__ bv2,
        float* __restrict__ out) {
    __shared__ float fr8[16][128];
    __shared__ float hh[16][128];
    __shared__ float dens[16][4];
    int tid = threadIdx.x;
    int r0 = blockIdx.x * 16;

    {
        int p = tid >> 3, sg = tid & 7;
        int r = p >> 2, hd = p & 3;
        float d = pden[(size_t)(sg * 4 + hd) * NN + r0 + r];
#pragma unroll
        for (int s = 4; s >= 1; s >>= 1) d += __shfl_xor(d, s, 8);
        if (sg == 0) dens[r][hd] = d;
    }

    int row = tid >> 5, c4 = (tid & 31) * 4;
    int hd2 = c4 >> 5;
    float o4[4] = {0.f, 0.f, 0.f, 0.f};
    const __half* pp = pout + ((size_t)hd2 * NN + r0 + row) * 32 + (c4 & 31);
#pragma unroll
    for (int s = 0; s < NSPLIT_FB; s++) {
        float2 raw = *(const float2*)(pp + (size_t)s * 4 * NN * 32);
        __half2 ha = *(__half2*)&raw.x;
        __half2 hb = *(__half2*)&raw.y;
        float2 fa = __half22float2(ha), fb = __half22float2(hb);
        o4[0] += fa.x; o4[1] += fa.y; o4[2] += fb.x; o4[3] += fb.y;
    }
    __syncthreads();
    {
        float dn = fmaxf(dens[row][hd2], 1e-30f);
#pragma unroll
        for (int i = 0; i < 4; i++) fr8[row][c4 + i] = o4[i] / dn;
    }
    __syncthreads();

    int c = tid & 127, g = tid >> 7;
    int c2 = tid & 31, r = tid >> 5;

    {
        float acc[4];
        float bb = bp1[c];
#pragma unroll
        for (int q = 0; q < 4; q++) acc[q] = bb;
#pragma unroll 8
        for (int k = 0; k < HID; k++) {
            float w = Wp1[k * HID + c];
#pragma unroll
            for (int q = 0; q < 4; q++) acc[q] += w * fr8[g * 4 + q][k];
        }
#pragma unroll
        for (int q = 0; q < 4; q++) hh[g * 4 + q][c] = fmaxf(acc[q], 0.f);
    }
    __syncthreads();
    {
        float lacc = bp2[c2];
#pragma unroll 8
        for (int k = 0; k < HID; k++) lacc += hh[r][k] * Wp2[k * 32 + c2];
        float mx = lacc;
#pragma unroll
        for (int s = 16; s >= 1; s >>= 1) mx = fmaxf(mx, __shfl_xor(mx, s, 32));
        float e = __expf(lacc - mx);
        float sm = e;
#pragma unroll
        for (int s = 16; s >= 1; s >>= 1) sm += __shfl_xor(sm, s, 32);
        out[(size_t)(r0 + r) * 32 + c2] = e / sm;
    }
    __syncthreads();
    {
        float acc[4];
        float bb = bv1[c];
#pragma unroll
        for (int q = 0; q < 4; q++) acc[q] = bb;
#pragma unroll 8
        for (int k = 0; k < HID; k++) {
            float w = Wv1[k * HID + c];
#pragma unroll
            for (int q = 0; q < 4; q++) acc[q] += w * fr8[g * 4 + q][k];
        }
#pragma unroll
        for (int q = 0; q < 4; q++) hh[g * 4 + q][c] = fmaxf(acc[q], 0.f);
    }
    __syncthreads();
    {
        float p = 0.f;
#pragma unroll
        for (int j = 0; j < 4; j++) p += hh[r][c2 + j * 32] * Wv2[c2 + j * 32];
#pragma unroll
        for (int s = 16; s >= 1; s >>= 1) p += __shfl_xor(p, s, 32);
        if (c2 == 0) out[131072 + r0 + r] = p + bv2[0];
    }
}

extern "C" void kernel_launch(void* const* d_in, const int* in_sizes, int n_in,
                              void* d_out, int out_size, void* d_ws, size_t ws_size,
                              hipStream_t stream) {
    const float* state = (const float*)d_in[0];
    const int*   adj   = (const int*)d_in[1];
    const float* W1  = (const float*)d_in[2];
    const float* b1  = (const float*)d_in[3];
    const float* W2  = (const float*)d_in[4];
    const float* b2  = (const float*)d_in[5];
    const float* Wg  = (const float*)d_in[6];
    const float* ag  = (const float*)d_in[7];
    const float* Wp1 = (const float*)d_in[8];
    const float* bp1 = (const float*)d_in[9];
    const float* Wp2 = (const float*)d_in[10];
    const float* bp2 = (const float*)d_in[11];
    const float* Wv1 = (const float*)d_in[12];
    const float* bv1 = (const float*)d_in[13];
    const float* Wv2 = (const float*)d_in[14];
    const float* bv2 = (const float*)d_in[15];
    float* out = (float*)d_out;
    float* ws = (float*)d_ws;

    unsigned short* hTf = (unsigned short*)ws;            // 524288 fp16
    float* s1b  = ws + 262144;
    float* s2b  = ws + 278528;
    unsigned int* abit = (unsigned int*)(ws + 294912);    // 2 MB
    __half* pout = (__half*)(ws + 819200);                // up to 8.4M fp16
    float* pden = ws + 5013504;

    // capture-safe host queries; deterministic per call
    int dev = 0;
    hipGetDevice(&dev);
    int nCU = 0;
    hipDeviceGetAttribute(&nCU, hipDeviceAttributeMultiprocessorCount, dev);
    int maxB = 0;
    hipError_t qe = hipOccupancyMaxActiveBlocksPerMultiprocessor(&maxB, k_fused, 256, 0);

    if (qe == hipSuccess && (long)maxB * nCU >= 512) {
        void* args[] = { (void*)&state, (void*)&W1, (void*)&b1, (void*)&W2, (void*)&b2,
                         (void*)&Wg, (void*)&ag, (void*)&adj,
                         (void*)&Wp1, (void*)&bp1, (void*)&Wp2, (void*)&bp2,
                         (void*)&Wv1, (void*)&bv1, (void*)&Wv2, (void*)&bv2,
                         (void*)&hTf, (void*)&s1b, (void*)&s2b, (void*)&abit,
                         (void*)&pout, (void*)&pden, (void*)&out };
        hipError_t le = hipLaunchCooperativeKernel((void*)k_fused, dim3(512), dim3(256),
                                                   args, 0, stream);
        if (le == hipSuccess) return;
    }

    // fallback: proven 3-kernel path
    hipLaunchKernelGGL(k_prep_pack, dim3(512 + NN), dim3(256), 0, stream,
                       state, W1, b1, W2, b2, Wg, ag, adj, hTf, s1b, s2b, abit);
    hipLaunchKernelGGL(k_attn_fb, dim3(32 * NSPLIT_FB * HEADS), dim3(256), 0, stream,
                       abit, hTf, s1b, s2b, pout, pden);
    hipLaunchKernelGGL(k_redpolval_fb, dim3(NN / 16), dim3(512), 0, stream,
                       pout, pden, Wp1, bp1, Wp2, bp2, Wv1, bv1, Wv2, bv2, out);
}